// Round 9
// baseline (672.109 us; speedup 1.0000x reference)
//
#include <hip/hip_runtime.h>
#include <hip/hip_cooperative_groups.h>
#include <cmath>

#define BB   2
#define LL   2048
#define DIMD 1024
#define NS   16
#define KC   4
#define ML   (BB*LL)        // 4096 rows (B*L)
#define XZ_N (2*DIMD)       // 2048
#define XD_N (2*NS + DIMD)  // 1056
#define LC   16             // scan chunk length
#define NC   (LL/LC)        // 128 chunks per sequence

typedef __attribute__((ext_vector_type(8))) short bf16x8;   // 8 bf16 (4 VGPRs)
typedef __attribute__((ext_vector_type(4))) float f32x4;    // MFMA acc

__device__ __forceinline__ unsigned short f2bf(float f) {
    union { float f; unsigned u; } v; v.f = f;
    unsigned r = v.u + 0x7FFF + ((v.u >> 16) & 1);   // round-to-nearest-even
    return (unsigned short)(r >> 16);
}
__device__ __forceinline__ float bf2f(unsigned short u) {
    union { unsigned u; float f; } v; v.u = (unsigned)u << 16;
    return v.f;
}

// ---------------------------------------------------------------------------
// Fused f32 -> bf16 conversion for x + the 3 weight matrices (one launch).
// ---------------------------------------------------------------------------
__global__ __launch_bounds__(256) void cvt_all(
    const float* __restrict__ s0, unsigned short* __restrict__ d0, int n0,
    const float* __restrict__ s1, unsigned short* __restrict__ d1, int n1,
    const float* __restrict__ s2, unsigned short* __restrict__ d2, int n2,
    const float* __restrict__ s3, unsigned short* __restrict__ d3, int n3)
{
    int i = blockIdx.x * blockDim.x + threadIdx.x;
    const float* src; unsigned short* dst;
    if (i < n0)                { src = s0; dst = d0; }
    else if ((i -= n0) < n1)   { src = s1; dst = d1; }
    else if ((i -= n1) < n2)   { src = s2; dst = d2; }
    else if ((i -= n2) < n3)   { src = s3; dst = d3; }
    else return;
    float4 f = ((const float4*)src)[i];
    ushort4 o;
    o.x = f2bf(f.x); o.y = f2bf(f.y); o.z = f2bf(f.z); o.w = f2bf(f.w);
    ((ushort4*)dst)[i] = o;
}

// ---------------------------------------------------------------------------
// bf16 MFMA GEMM, C = A[M,K] @ W[N,K]^T. 128x128 tile, BK=64, 4 waves,
// mfma_f32_16x16x32_bf16 4x4 frags, global_load_lds w=16, XOR-8 swizzle.
// Epilogue: cols < nsplit -> f32 store (row stride = nsplit);
//           nsplit <= col < N -> silu + bf16 store to zb (row stride DIMD).
// ---------------------------------------------------------------------------
__global__ __launch_bounds__(256) void gemm_mfma_bt(
    const unsigned short* __restrict__ A,
    const unsigned short* __restrict__ Bw,
    float* __restrict__ C,
    unsigned short* __restrict__ zb,
    int M, int N, int K, int nsplit)
{
    __shared__ short As[128 * 64];
    __shared__ short Bs[128 * 64];

    const int tid  = threadIdx.x;
    const int lane = tid & 63;
    const int wave = tid >> 6;
    const int bm = blockIdx.y * 128;
    const int bn = blockIdx.x * 128;
    const int wm = (wave >> 1) * 64;
    const int wn = (wave & 1) * 64;
    const int l15  = lane & 15;
    const int quad = lane >> 4;

    f32x4 acc[4][4];
    #pragma unroll
    for (int i = 0; i < 4; ++i)
        #pragma unroll
        for (int j = 0; j < 4; ++j)
            acc[i][j] = (f32x4){0.f, 0.f, 0.f, 0.f};

    for (int k0 = 0; k0 < K; k0 += 64) {
        __syncthreads();
        #pragma unroll
        for (int q = 0; q < 4; ++q) {
            const int ci = q * 256 + tid;
            const int r  = ci >> 3;
            const int cc = (ci & 7) ^ (r & 7);
            short* ldsA = As + (size_t)(q * 256 + (tid & ~63)) * 8;
            short* ldsB = Bs + (size_t)(q * 256 + (tid & ~63)) * 8;
            const unsigned short* ga = A + (size_t)(bm + r) * K + k0 + cc * 8;
            int rb = bn + r; if (rb > N - 1) rb = N - 1;
            const unsigned short* gb = Bw + (size_t)rb * K + k0 + cc * 8;
            __builtin_amdgcn_global_load_lds(
                (const __attribute__((address_space(1))) void*)ga,
                (__attribute__((address_space(3))) void*)ldsA, 16, 0, 0);
            __builtin_amdgcn_global_load_lds(
                (const __attribute__((address_space(1))) void*)gb,
                (__attribute__((address_space(3))) void*)ldsB, 16, 0, 0);
        }
        __syncthreads();

        #pragma unroll
        for (int kh = 0; kh < 2; ++kh) {
            bf16x8 af[4], bfr[4];
            #pragma unroll
            for (int i = 0; i < 4; ++i) {
                const int row = wm + i * 16 + l15;
                const int pc  = (kh * 4 + quad) ^ (row & 7);
                af[i] = *(const bf16x8*)(As + row * 64 + pc * 8);
            }
            #pragma unroll
            for (int j = 0; j < 4; ++j) {
                const int row = wn + j * 16 + l15;
                const int pc  = (kh * 4 + quad) ^ (row & 7);
                bfr[j] = *(const bf16x8*)(Bs + row * 64 + pc * 8);
            }
            #pragma unroll
            for (int i = 0; i < 4; ++i)
                #pragma unroll
                for (int j = 0; j < 4; ++j)
                    acc[i][j] = __builtin_amdgcn_mfma_f32_16x16x32_bf16(
                        af[i], bfr[j], acc[i][j], 0, 0, 0);
        }
    }

    #pragma unroll
    for (int i = 0; i < 4; ++i) {
        const int rbase = bm + wm + i * 16 + quad * 4;
        #pragma unroll
        for (int j = 0; j < 4; ++j) {
            const int col = bn + wn + j * 16 + l15;
            if (col < nsplit) {
                #pragma unroll
                for (int r = 0; r < 4; ++r)
                    C[(size_t)(rbase + r) * nsplit + col] = acc[i][j][r];
            } else if (col < N) {
                const int zc = col - nsplit;
                #pragma unroll
                for (int r = 0; r < 4; ++r) {
                    const float v = acc[i][j][r];
                    zb[(size_t)(rbase + r) * DIMD + zc] =
                        f2bf(v / (1.f + expf(-v)));
                }
            }
        }
    }
}

// ---------------------------------------------------------------------------
// Depthwise causal conv (K=4) + bias + SiLU, 4 channels per thread (float4).
// ---------------------------------------------------------------------------
__global__ __launch_bounds__(256) void conv_silu(const float* __restrict__ xcraw,
                                                 const float* __restrict__ w,
                                                 const float* __restrict__ bias,
                                                 float* __restrict__ xc,
                                                 unsigned short* __restrict__ xcb)
{
    const int i4 = blockIdx.x * blockDim.x + threadIdx.x;  // ML*DIMD/4
    if (i4 >= ML * DIMD / 4) return;
    const int dq = i4 & (DIMD / 4 - 1);    // d/4
    const int bl = i4 >> 8;                // b*L + l
    const int l  = bl & (LL - 1);

    const float4 wq0 = ((const float4*)w)[dq * 4 + 0];
    const float4 wq1 = ((const float4*)w)[dq * 4 + 1];
    const float4 wq2 = ((const float4*)w)[dq * 4 + 2];
    const float4 wq3 = ((const float4*)w)[dq * 4 + 3];
    const float4 bv  = ((const float4*)bias)[dq];

    const float* p = xcraw + (size_t)bl * DIMD + dq * 4;
    const float4 z4 = make_float4(0.f, 0.f, 0.f, 0.f);
    const float4 x0 = (l >= 3) ? *(const float4*)(p - 3 * DIMD) : z4;
    const float4 x1 = (l >= 2) ? *(const float4*)(p - 2 * DIMD) : z4;
    const float4 x2 = (l >= 1) ? *(const float4*)(p - 1 * DIMD) : z4;
    const float4 x3 = *(const float4*)p;

    float4 a;
    a.x = bv.x + wq0.x*x0.x + wq0.y*x1.x + wq0.z*x2.x + wq0.w*x3.x;
    a.y = bv.y + wq1.x*x0.y + wq1.y*x1.y + wq1.z*x2.y + wq1.w*x3.y;
    a.z = bv.z + wq2.x*x0.z + wq2.y*x1.z + wq2.z*x2.z + wq2.w*x3.z;
    a.w = bv.w + wq3.x*x0.w + wq3.y*x1.w + wq3.z*x2.w + wq3.w*x3.w;

    float4 v;
    v.x = a.x / (1.f + expf(-a.x));
    v.y = a.y / (1.f + expf(-a.y));
    v.z = a.z / (1.f + expf(-a.z));
    v.w = a.w / (1.f + expf(-a.w));

    ((float4*)xc)[i4] = v;
    ushort4 o;
    o.x = f2bf(v.x); o.y = f2bf(v.y); o.z = f2bf(v.z); o.w = f2bf(v.w);
    ((ushort4*)xcb)[i4] = o;
}

__device__ __forceinline__ float softplus_f(float x) {
    return (x > 20.f) ? x : log1pf(expf(x));
}

// ---------------------------------------------------------------------------
// Scan pass 1 (fallback path): local scan from h=0; emit h[16] + S=sum(dt).
// ---------------------------------------------------------------------------
__global__ __launch_bounds__(256) void scan_part1(const float* __restrict__ xdbl,
                                                  const float* __restrict__ xc,
                                                  float* __restrict__ hfin,
                                                  float* __restrict__ Ssum)
{
    __shared__ float Bsh[LC][NS];   // 1 KB

    const int tid = threadIdx.x;
    const int idx = blockIdx.x * 256 + tid;   // global (b,c,d)
    const int d   = idx & (DIMD - 1);
    const int bc  = idx >> 10;
    const int c   = bc & (NC - 1);
    const int b   = bc >> 7;
    const int l0  = c * LC;

    const float* xdbl_p = xdbl + ((size_t)b * LL + l0) * XD_N;
    const float* xc_p   = xc   + ((size_t)b * LL + l0) * DIMD + d;

    if (tid < LC * NS / 4) {               // 64 threads stage 16x16 B block
        const int l = tid >> 2, q = tid & 3;
        ((float4*)&Bsh[l][0])[q] = ((const float4*)(xdbl_p + (size_t)l * XD_N))[q];
    }
    __syncthreads();

    float raw[LC], xcv[LC];
    #pragma unroll
    for (int i = 0; i < LC; ++i) raw[i] = xdbl_p[(size_t)i * XD_N + 2 * NS + d];
    #pragma unroll
    for (int i = 0; i < LC; ++i) xcv[i] = xc_p[(size_t)i * DIMD];

    float e[LC], dx[LC];
    float S = 0.f;
    #pragma unroll
    for (int i = 0; i < LC; ++i) {
        const float dt = softplus_f(raw[i]);
        S += dt;
        e[i]  = expf(-dt);
        dx[i] = dt * xcv[i];
    }

    float h[NS];
    #pragma unroll
    for (int n = 0; n < NS; ++n) h[n] = 0.f;

    #pragma unroll
    for (int i = 0; i < LC; ++i) {
        const float4* BC = (const float4*)&Bsh[i][0];
        const float4 B0 = BC[0], B1 = BC[1], B2 = BC[2], B3 = BC[3];
        const float ev = e[i], dxv = dx[i];
        const float e2 = ev * ev, e4 = e2 * e2;
        float p0 = ev, p1 = e2, p2 = e2 * ev, p3 = e4;
        h[0]  = fmaf(h[0],  p0, dxv * B0.x);
        h[1]  = fmaf(h[1],  p1, dxv * B0.y);
        h[2]  = fmaf(h[2],  p2, dxv * B0.z);
        h[3]  = fmaf(h[3],  p3, dxv * B0.w);
        p0 *= e4; p1 *= e4; p2 *= e4; p3 *= e4;
        h[4]  = fmaf(h[4],  p0, dxv * B1.x);
        h[5]  = fmaf(h[5],  p1, dxv * B1.y);
        h[6]  = fmaf(h[6],  p2, dxv * B1.z);
        h[7]  = fmaf(h[7],  p3, dxv * B1.w);
        p0 *= e4; p1 *= e4; p2 *= e4; p3 *= e4;
        h[8]  = fmaf(h[8],  p0, dxv * B2.x);
        h[9]  = fmaf(h[9],  p1, dxv * B2.y);
        h[10] = fmaf(h[10], p2, dxv * B2.z);
        h[11] = fmaf(h[11], p3, dxv * B2.w);
        p0 *= e4; p1 *= e4; p2 *= e4; p3 *= e4;
        h[12] = fmaf(h[12], p0, dxv * B3.x);
        h[13] = fmaf(h[13], p1, dxv * B3.y);
        h[14] = fmaf(h[14], p2, dxv * B3.z);
        h[15] = fmaf(h[15], p3, dxv * B3.w);
    }

    float4* hf = (float4*)(hfin + (size_t)idx * NS);
    #pragma unroll
    for (int n = 0; n < 4; ++n) hf[n] = ((float4*)h)[n];
    Ssum[idx] = S;
}

// ---------------------------------------------------------------------------
// Scan pass 2 (fallback): batched 8-wide prefetch + off-chain expf; hfin
// rewritten in place to carry-in states.
// ---------------------------------------------------------------------------
__global__ __launch_bounds__(256) void scan_combine(float* __restrict__ hfin,
                                                    const float* __restrict__ Ssum)
{
    const int idx = blockIdx.x * blockDim.x + threadIdx.x;  // B*DIMD*NS
    const int n = idx & (NS - 1);
    const int d = (idx >> 4) & (DIMD - 1);
    const int b = idx >> 14;
    const float np1 = (float)(n + 1);

    float hc = 0.f;
    for (int c0 = 0; c0 < NC; c0 += 8) {
        float Sb[8], hb[8], eb[8];
        #pragma unroll
        for (int j = 0; j < 8; ++j) {
            const size_t base = ((size_t)(b * NC + c0 + j) * DIMD + d);
            Sb[j] = Ssum[base];
            hb[j] = hfin[base * NS + n];
        }
        #pragma unroll
        for (int j = 0; j < 8; ++j) eb[j] = expf(-Sb[j] * np1);
        #pragma unroll
        for (int j = 0; j < 8; ++j) {
            const size_t o = ((size_t)(b * NC + c0 + j) * DIMD + d) * NS + n;
            hfin[o] = hc;
            hc = fmaf(hc, eb[j], hb[j]);
        }
    }
}

// ---------------------------------------------------------------------------
// Scan pass 3 (fallback): seeded re-scan + y + D*xc + z-gate + bf16 store.
// ---------------------------------------------------------------------------
__global__ __launch_bounds__(256) void scan_part2(const float* __restrict__ xdbl,
                                                  const float* __restrict__ xc,
                                                  const unsigned short* __restrict__ zb,
                                                  const float* __restrict__ hfin,
                                                  const float* __restrict__ Dp,
                                                  unsigned short* __restrict__ yout)
{
    __shared__ float BCs[LC][2 * NS];   // 2 KB

    const int tid = threadIdx.x;
    const int idx = blockIdx.x * 256 + tid;
    const int d   = idx & (DIMD - 1);
    const int bc  = idx >> 10;
    const int c   = bc & (NC - 1);
    const int b   = bc >> 7;
    const int l0  = c * LC;

    const float* xdbl_p = xdbl + ((size_t)b * LL + l0) * XD_N;
    const float* xc_p   = xc   + ((size_t)b * LL + l0) * DIMD + d;
    const unsigned short* zb_p = zb + ((size_t)b * LL + l0) * DIMD + d;
    unsigned short* y_p = yout + ((size_t)b * LL + l0) * DIMD + d;

    if (tid < LC * 2 * NS / 4) {
        const int l = tid >> 3, q = tid & 7;
        ((float4*)&BCs[l][0])[q] = ((const float4*)(xdbl_p + (size_t)l * XD_N))[q];
    }
    __syncthreads();

    float raw[LC], xcv[LC], zg[LC];
    #pragma unroll
    for (int i = 0; i < LC; ++i) raw[i] = xdbl_p[(size_t)i * XD_N + 2 * NS + d];
    #pragma unroll
    for (int i = 0; i < LC; ++i) xcv[i] = xc_p[(size_t)i * DIMD];
    #pragma unroll
    for (int i = 0; i < LC; ++i) zg[i] = bf2f(zb_p[(size_t)i * DIMD]);

    float e[LC], dx[LC];
    #pragma unroll
    for (int i = 0; i < LC; ++i) {
        const float dt = softplus_f(raw[i]);
        e[i]  = expf(-dt);
        dx[i] = dt * xcv[i];
    }

    const float Dv = Dp[d];
    float h[NS];
    {
        const float4* hf = (const float4*)(hfin + (size_t)idx * NS);
        #pragma unroll
        for (int n = 0; n < 4; ++n) ((float4*)h)[n] = hf[n];
    }

    #pragma unroll
    for (int i = 0; i < LC; ++i) {
        const float4* BC = (const float4*)&BCs[i][0];
        const float4 B0 = BC[0], B1 = BC[1], B2 = BC[2], B3 = BC[3];
        const float4 C0 = BC[4], C1 = BC[5], C2 = BC[6], C3 = BC[7];
        const float ev = e[i], dxv = dx[i];
        const float e2 = ev * ev, e4 = e2 * e2;
        float p0 = ev, p1 = e2, p2 = e2 * ev, p3 = e4;
        float y0, y1, y2, y3;
        h[0]  = fmaf(h[0],  p0, dxv * B0.x); y0 = h[0]  * C0.x;
        h[1]  = fmaf(h[1],  p1, dxv * B0.y); y1 = h[1]  * C0.y;
        h[2]  = fmaf(h[2],  p2, dxv * B0.z); y2 = h[2]  * C0.z;
        h[3]  = fmaf(h[3],  p3, dxv * B0.w); y3 = h[3]  * C0.w;
        p0 *= e4; p1 *= e4; p2 *= e4; p3 *= e4;
        h[4]  = fmaf(h[4],  p0, dxv * B1.x); y0 = fmaf(h[4],  C1.x, y0);
        h[5]  = fmaf(h[5],  p1, dxv * B1.y); y1 = fmaf(h[5],  C1.y, y1);
        h[6]  = fmaf(h[6],  p2, dxv * B1.z); y2 = fmaf(h[6],  C1.z, y2);
        h[7]  = fmaf(h[7],  p3, dxv * B1.w); y3 = fmaf(h[7],  C1.w, y3);
        p0 *= e4; p1 *= e4; p2 *= e4; p3 *= e4;
        h[8]  = fmaf(h[8],  p0, dxv * B2.x); y0 = fmaf(h[8],  C2.x, y0);
        h[9]  = fmaf(h[9],  p1, dxv * B2.y); y1 = fmaf(h[9],  C2.y, y1);
        h[10] = fmaf(h[10], p2, dxv * B2.z); y2 = fmaf(h[10], C2.z, y2);
        h[11] = fmaf(h[11], p3, dxv * B2.w); y3 = fmaf(h[11], C2.w, y3);
        p0 *= e4; p1 *= e4; p2 *= e4; p3 *= e4;
        h[12] = fmaf(h[12], p0, dxv * B3.x); y0 = fmaf(h[12], C3.x, y0);
        h[13] = fmaf(h[13], p1, dxv * B3.y); y1 = fmaf(h[13], C3.y, y1);
        h[14] = fmaf(h[14], p2, dxv * B3.z); y2 = fmaf(h[14], C3.z, y2);
        h[15] = fmaf(h[15], p3, dxv * B3.w); y3 = fmaf(h[15], C3.w, y3);

        const float y  = (y0 + y1) + (y2 + y3);
        const float yv = fmaf(Dv, xcv[i], y);
        y_p[(size_t)i * DIMD] = f2bf(yv * zg[i]);
    }
}

// ---------------------------------------------------------------------------
// FUSED cooperative scan (attempted first; harness falls back on error).
// ---------------------------------------------------------------------------
__global__ __launch_bounds__(256, 4) void scan_fused(
    const float* __restrict__ xdbl,
    const float* __restrict__ xc,
    const unsigned short* __restrict__ zb,
    const float* __restrict__ Dp,
    float* __restrict__ hfin,
    float* __restrict__ Ssum,
    unsigned short* __restrict__ yout)
{
    __shared__ float BCs[LC][2 * NS];

    const int tid = threadIdx.x;
    const int idx = blockIdx.x * 256 + tid;
    const int d   = idx & (DIMD - 1);
    const int bc  = idx >> 10;
    const int c   = bc & (NC - 1);
    const int b   = bc >> 7;
    const int l0  = c * LC;

    const float* xdbl_p = xdbl + ((size_t)b * LL + l0) * XD_N;
    const float* xc_p   = xc   + ((size_t)b * LL + l0) * DIMD + d;
    const unsigned short* zb_p = zb + ((size_t)b * LL + l0) * DIMD + d;
    unsigned short* y_p = yout + ((size_t)b * LL + l0) * DIMD + d;

    if (tid < LC * 2 * NS / 4) {
        const int l = tid >> 3, q = tid & 7;
        ((float4*)&BCs[l][0])[q] = ((const float4*)(xdbl_p + (size_t)l * XD_N))[q];
    }
    __syncthreads();

    float raw[LC], xcv[LC];
    #pragma unroll
    for (int i = 0; i < LC; ++i) raw[i] = xdbl_p[(size_t)i * XD_N + 2 * NS + d];
    #pragma unroll
    for (int i = 0; i < LC; ++i) xcv[i] = xc_p[(size_t)i * DIMD];

    float e[LC], dx[LC];
    float S = 0.f;
    #pragma unroll
    for (int i = 0; i < LC; ++i) {
        const float dt = softplus_f(raw[i]);
        S += dt;
        e[i]  = expf(-dt);
        dx[i] = dt * xcv[i];
    }

    float h[NS];
    #pragma unroll
    for (int n = 0; n < NS; ++n) h[n] = 0.f;

    #pragma unroll
    for (int i = 0; i < LC; ++i) {
        const float4* BC = (const float4*)&BCs[i][0];
        const float4 B0 = BC[0], B1 = BC[1], B2 = BC[2], B3 = BC[3];
        const float ev = e[i], dxv = dx[i];
        const float e2 = ev * ev, e4 = e2 * e2;
        float p0 = ev, p1 = e2, p2 = e2 * ev, p3 = e4;
        h[0]  = fmaf(h[0],  p0, dxv * B0.x);
        h[1]  = fmaf(h[1],  p1, dxv * B0.y);
        h[2]  = fmaf(h[2],  p2, dxv * B0.z);
        h[3]  = fmaf(h[3],  p3, dxv * B0.w);
        p0 *= e4; p1 *= e4; p2 *= e4; p3 *= e4;
        h[4]  = fmaf(h[4],  p0, dxv * B1.x);
        h[5]  = fmaf(h[5],  p1, dxv * B1.y);
        h[6]  = fmaf(h[6],  p2, dxv * B1.z);
        h[7]  = fmaf(h[7],  p3, dxv * B1.w);
        p0 *= e4; p1 *= e4; p2 *= e4; p3 *= e4;
        h[8]  = fmaf(h[8],  p0, dxv * B2.x);
        h[9]  = fmaf(h[9],  p1, dxv * B2.y);
        h[10] = fmaf(h[10], p2, dxv * B2.z);
        h[11] = fmaf(h[11], p3, dxv * B2.w);
        p0 *= e4; p1 *= e4; p2 *= e4; p3 *= e4;
        h[12] = fmaf(h[12], p0, dxv * B3.x);
        h[13] = fmaf(h[13], p1, dxv * B3.y);
        h[14] = fmaf(h[14], p2, dxv * B3.z);
        h[15] = fmaf(h[15], p3, dxv * B3.w);
    }

    {
        float4* hf = (float4*)(hfin + (size_t)idx * NS);
        #pragma unroll
        for (int n = 0; n < 4; ++n) hf[n] = ((float4*)h)[n];
        Ssum[idx] = S;
    }

    cooperative_groups::this_grid().sync();

    const int gid = blockIdx.x * 256 + tid;
    if (gid < BB * DIMD * NS) {
        const int cn = gid & (NS - 1);
        const int cd = (gid >> 4) & (DIMD - 1);
        const int cb = gid >> 14;
        const float np1 = (float)(cn + 1);

        float hc = 0.f;
        for (int c0 = 0; c0 < NC; c0 += 8) {
            float Sb[8], hb[8], eb[8];
            #pragma unroll
            for (int j = 0; j < 8; ++j) {
                const size_t base = ((size_t)(cb * NC + c0 + j) * DIMD + cd);
                Sb[j] = Ssum[base];
                hb[j] = hfin[base * NS + cn];
            }
            #pragma unroll
            for (int j = 0; j < 8; ++j) eb[j] = expf(-Sb[j] * np1);
            #pragma unroll
            for (int j = 0; j < 8; ++j) {
                const size_t o = ((size_t)(cb * NC + c0 + j) * DIMD + cd) * NS + cn;
                hfin[o] = hc;
                hc = fmaf(hc, eb[j], hb[j]);
            }
        }
    }

    cooperative_groups::this_grid().sync();

    {
        const float4* hf = (const float4*)(hfin + (size_t)idx * NS);
        #pragma unroll
        for (int n = 0; n < 4; ++n) ((float4*)h)[n] = hf[n];
    }

    float zg[LC];
    #pragma unroll
    for (int i = 0; i < LC; ++i) zg[i] = bf2f(zb_p[(size_t)i * DIMD]);

    const float Dv = Dp[d];

    #pragma unroll
    for (int i = 0; i < LC; ++i) {
        const float4* BC = (const float4*)&BCs[i][0];
        const float4 B0 = BC[0], B1 = BC[1], B2 = BC[2], B3 = BC[3];
        const float4 C0 = BC[4], C1 = BC[5], C2 = BC[6], C3 = BC[7];
        const float ev = e[i], dxv = dx[i];
        const float e2 = ev * ev, e4 = e2 * e2;
        float p0 = ev, p1 = e2, p2 = e2 * ev, p3 = e4;
        float y0, y1, y2, y3;
        h[0]  = fmaf(h[0],  p0, dxv * B0.x); y0 = h[0]  * C0.x;
        h[1]  = fmaf(h[1],  p1, dxv * B0.y); y1 = h[1]  * C0.y;
        h[2]  = fmaf(h[2],  p2, dxv * B0.z); y2 = h[2]  * C0.z;
        h[3]  = fmaf(h[3],  p3, dxv * B0.w); y3 = h[3]  * C0.w;
        p0 *= e4; p1 *= e4; p2 *= e4; p3 *= e4;
        h[4]  = fmaf(h[4],  p0, dxv * B1.x); y0 = fmaf(h[4],  C1.x, y0);
        h[5]  = fmaf(h[5],  p1, dxv * B1.y); y1 = fmaf(h[5],  C1.y, y1);
        h[6]  = fmaf(h[6],  p2, dxv * B1.z); y2 = fmaf(h[6],  C1.z, y2);
        h[7]  = fmaf(h[7],  p3, dxv * B1.w); y3 = fmaf(h[7],  C1.w, y3);
        p0 *= e4; p1 *= e4; p2 *= e4; p3 *= e4;
        h[8]  = fmaf(h[8],  p0, dxv * B2.x); y0 = fmaf(h[8],  C2.x, y0);
        h[9]  = fmaf(h[9],  p1, dxv * B2.y); y1 = fmaf(h[9],  C2.y, y1);
        h[10] = fmaf(h[10], p2, dxv * B2.z); y2 = fmaf(h[10], C2.z, y2);
        h[11] = fmaf(h[11], p3, dxv * B2.w); y3 = fmaf(h[11], C2.w, y3);
        p0 *= e4; p1 *= e4; p2 *= e4; p3 *= e4;
        h[12] = fmaf(h[12], p0, dxv * B3.x); y0 = fmaf(h[12], C3.x, y0);
        h[13] = fmaf(h[13], p1, dxv * B3.y); y1 = fmaf(h[13], C3.y, y1);
        h[14] = fmaf(h[14], p2, dxv * B3.z); y2 = fmaf(h[14], C3.z, y2);
        h[15] = fmaf(h[15], p3, dxv * B3.w); y3 = fmaf(h[15], C3.w, y3);

        const float y  = (y0 + y1) + (y2 + y3);
        const float yv = fmaf(Dv, xcv[i], y);
        y_p[(size_t)i * DIMD] = f2bf(yv * zg[i]);
    }
}

extern "C" void kernel_launch(void* const* d_in, const int* in_sizes, int n_in,
                              void* d_out, int out_size, void* d_ws, size_t ws_size,
                              hipStream_t stream)
{
    const float* x          = (const float*)d_in[0];
    const float* in_proj_w  = (const float*)d_in[1];
    const float* conv_w     = (const float*)d_in[2];
    const float* conv_b     = (const float*)d_in[3];
    const float* x_proj_w   = (const float*)d_in[4];
    const float* D_param    = (const float*)d_in[5];
    const float* out_proj_w = (const float*)d_in[6];
    float* out = (float*)d_out;

    // workspace layout (~84.5 MiB)
    float* xcraw = (float*)d_ws;                              // ML*DIMD f32
    float* xc    = xcraw + (size_t)ML * DIMD;                 // ML*DIMD f32
    float* xdbl  = xc    + (size_t)ML * DIMD;                 // ML*XD_N f32
    unsigned short* zb  = (unsigned short*)(xdbl + (size_t)ML * XD_N); // ML*DIMD bf16
    unsigned short* xb  = zb  + (size_t)ML * DIMD;            // ML*DIMD bf16
    unsigned short* xcb = xb  + (size_t)ML * DIMD;            // ML*DIMD bf16
    unsigned short* wb1 = xcb + (size_t)ML * DIMD;            // XZ_N*DIMD bf16
    unsigned short* wb2 = wb1 + (size_t)XZ_N * DIMD;          // XD_N*DIMD bf16
    unsigned short* wb3 = wb2 + (size_t)XD_N * DIMD;          // DIMD*DIMD bf16
    unsigned short* yb  = xb;    // xb dead after GEMM1; reuse for scan output

    // hfin: B*NC*DIMD*NS floats = 16.8 MB = exact fit in d_out (dead till GEMM3)
    float* hfin = out;
    // Ssum: 1 MB, aliases wb1 (dead after GEMM1; scan runs after GEMM2)
    float* Ssum = (float*)wb1;

    const int n0 = ML * DIMD / 4, n1 = XZ_N * DIMD / 4,
              n2 = XD_N * DIMD / 4, n3 = DIMD * DIMD / 4;
    const int ncvt = n0 + n1 + n2 + n3;

    // 0) all f32->bf16 conversions in one launch
    cvt_all<<<(ncvt + 255) / 256, 256, 0, stream>>>(
        x, xb, n0, in_proj_w, wb1, n1, x_proj_w, wb2, n2, out_proj_w, wb3, n3);

    // 1) xz = x @ in_proj_w.T; x_c half -> f32 xcraw, z half -> silu bf16 zb
    gemm_mfma_bt<<<dim3(XZ_N / 128, ML / 128), 256, 0, stream>>>(
        xb, wb1, xcraw, zb, ML, XZ_N, DIMD, DIMD);

    // 2) depthwise conv + bias + silu -> xc (f32) + xcb (bf16)
    conv_silu<<<(ML * DIMD / 4) / 256, 256, 0, stream>>>(
        xcraw, conv_w, conv_b, xc, xcb);

    // 3) x_dbl = xc @ x_proj_w.T     (4096 x 1056 x 1024)
    gemm_mfma_bt<<<dim3((XD_N + 127) / 128, ML / 128), 256, 0, stream>>>(
        xcb, wb2, xdbl, nullptr, ML, XD_N, DIMD, XD_N);

    // 4) selective scan: try fused cooperative; on ANY error fall back to the
    //    proven 3-kernel path (identical math). Deterministic per-call.
    {
        void* args[] = { (void*)&xdbl, (void*)&xc, (void*)&zb, (void*)&D_param,
                         (void*)&hfin, (void*)&Ssum, (void*)&yb };
        hipError_t rc = hipLaunchCooperativeKernel(
            (const void*)scan_fused, dim3(BB * NC * DIMD / 256), dim3(256),
            args, 0, stream);
        if (rc != hipSuccess) {
            scan_part1<<<(BB * NC * DIMD) / 256, 256, 0, stream>>>(
                xdbl, xc, hfin, Ssum);
            scan_combine<<<(BB * DIMD * NS) / 256, 256, 0, stream>>>(hfin, Ssum);
            scan_part2<<<(BB * NC * DIMD) / 256, 256, 0, stream>>>(
                xdbl, xc, zb, hfin, D_param, yb);
        }
    }

    // 5) out = y @ out_proj_w.T      (4096 x 1024 x 1024)
    gemm_mfma_bt<<<dim3(DIMD / 128, ML / 128), 256, 0, stream>>>(
        yb, wb3, out, nullptr, ML, DIMD, DIMD, DIMD);
}

// Round 10
// 250.729 us; speedup vs baseline: 2.6806x; 2.6806x over previous
//
#include <hip/hip_runtime.h>
#include <cmath>

#define BB   2
#define LL   2048
#define DIMD 1024
#define NS   16
#define KC   4
#define ML   (BB*LL)        // 4096 rows (B*L)
#define XZ_N (2*DIMD)       // 2048
#define XD_N (2*NS + DIMD)  // 1056
#define LC   16             // scan chunk length
#define NC   (LL/LC)        // 128 chunks per sequence

typedef __attribute__((ext_vector_type(8))) short bf16x8;   // 8 bf16 (4 VGPRs)
typedef __attribute__((ext_vector_type(4))) float f32x4;    // MFMA acc

__device__ __forceinline__ unsigned short f2bf(float f) {
    union { float f; unsigned u; } v; v.f = f;
    unsigned r = v.u + 0x7FFF + ((v.u >> 16) & 1);   // round-to-nearest-even
    return (unsigned short)(r >> 16);
}
__device__ __forceinline__ float bf2f(unsigned short u) {
    union { unsigned u; float f; } v; v.u = (unsigned)u << 16;
    return v.f;
}

// ---------------------------------------------------------------------------
// Fused f32 -> bf16 conversion for x + the 3 weight matrices (one launch).
// ---------------------------------------------------------------------------
__global__ __launch_bounds__(256) void cvt_all(
    const float* __restrict__ s0, unsigned short* __restrict__ d0, int n0,
    const float* __restrict__ s1, unsigned short* __restrict__ d1, int n1,
    const float* __restrict__ s2, unsigned short* __restrict__ d2, int n2,
    const float* __restrict__ s3, unsigned short* __restrict__ d3, int n3)
{
    int i = blockIdx.x * blockDim.x + threadIdx.x;
    const float* src; unsigned short* dst;
    if (i < n0)                { src = s0; dst = d0; }
    else if ((i -= n0) < n1)   { src = s1; dst = d1; }
    else if ((i -= n1) < n2)   { src = s2; dst = d2; }
    else if ((i -= n2) < n3)   { src = s3; dst = d3; }
    else return;
    float4 f = ((const float4*)src)[i];
    ushort4 o;
    o.x = f2bf(f.x); o.y = f2bf(f.y); o.z = f2bf(f.z); o.w = f2bf(f.w);
    ((ushort4*)dst)[i] = o;
}

// ---------------------------------------------------------------------------
// bf16 MFMA GEMM, C = A[M,K] @ W[N,K]^T. 128x128 tile, BK=64, 4 waves,
// mfma_f32_16x16x32_bf16 4x4 frags, global_load_lds w=16, XOR-8 swizzle.
// Epilogue: cols < nsplit -> f32 store (row stride = nsplit);
//           nsplit <= col < N -> silu + bf16 store to zb (row stride DIMD).
// ---------------------------------------------------------------------------
__global__ __launch_bounds__(256) void gemm_mfma_bt(
    const unsigned short* __restrict__ A,
    const unsigned short* __restrict__ Bw,
    float* __restrict__ C,
    unsigned short* __restrict__ zb,
    int M, int N, int K, int nsplit)
{
    __shared__ short As[128 * 64];
    __shared__ short Bs[128 * 64];

    const int tid  = threadIdx.x;
    const int lane = tid & 63;
    const int wave = tid >> 6;
    const int bm = blockIdx.y * 128;
    const int bn = blockIdx.x * 128;
    const int wm = (wave >> 1) * 64;
    const int wn = (wave & 1) * 64;
    const int l15  = lane & 15;
    const int quad = lane >> 4;

    f32x4 acc[4][4];
    #pragma unroll
    for (int i = 0; i < 4; ++i)
        #pragma unroll
        for (int j = 0; j < 4; ++j)
            acc[i][j] = (f32x4){0.f, 0.f, 0.f, 0.f};

    for (int k0 = 0; k0 < K; k0 += 64) {
        __syncthreads();
        #pragma unroll
        for (int q = 0; q < 4; ++q) {
            const int ci = q * 256 + tid;
            const int r  = ci >> 3;
            const int cc = (ci & 7) ^ (r & 7);
            short* ldsA = As + (size_t)(q * 256 + (tid & ~63)) * 8;
            short* ldsB = Bs + (size_t)(q * 256 + (tid & ~63)) * 8;
            const unsigned short* ga = A + (size_t)(bm + r) * K + k0 + cc * 8;
            int rb = bn + r; if (rb > N - 1) rb = N - 1;
            const unsigned short* gb = Bw + (size_t)rb * K + k0 + cc * 8;
            __builtin_amdgcn_global_load_lds(
                (const __attribute__((address_space(1))) void*)ga,
                (__attribute__((address_space(3))) void*)ldsA, 16, 0, 0);
            __builtin_amdgcn_global_load_lds(
                (const __attribute__((address_space(1))) void*)gb,
                (__attribute__((address_space(3))) void*)ldsB, 16, 0, 0);
        }
        __syncthreads();

        #pragma unroll
        for (int kh = 0; kh < 2; ++kh) {
            bf16x8 af[4], bfr[4];
            #pragma unroll
            for (int i = 0; i < 4; ++i) {
                const int row = wm + i * 16 + l15;
                const int pc  = (kh * 4 + quad) ^ (row & 7);
                af[i] = *(const bf16x8*)(As + row * 64 + pc * 8);
            }
            #pragma unroll
            for (int j = 0; j < 4; ++j) {
                const int row = wn + j * 16 + l15;
                const int pc  = (kh * 4 + quad) ^ (row & 7);
                bfr[j] = *(const bf16x8*)(Bs + row * 64 + pc * 8);
            }
            #pragma unroll
            for (int i = 0; i < 4; ++i)
                #pragma unroll
                for (int j = 0; j < 4; ++j)
                    acc[i][j] = __builtin_amdgcn_mfma_f32_16x16x32_bf16(
                        af[i], bfr[j], acc[i][j], 0, 0, 0);
        }
    }

    #pragma unroll
    for (int i = 0; i < 4; ++i) {
        const int rbase = bm + wm + i * 16 + quad * 4;
        #pragma unroll
        for (int j = 0; j < 4; ++j) {
            const int col = bn + wn + j * 16 + l15;
            if (col < nsplit) {
                #pragma unroll
                for (int r = 0; r < 4; ++r)
                    C[(size_t)(rbase + r) * nsplit + col] = acc[i][j][r];
            } else if (col < N) {
                const int zc = col - nsplit;
                #pragma unroll
                for (int r = 0; r < 4; ++r) {
                    const float v = acc[i][j][r];
                    zb[(size_t)(rbase + r) * DIMD + zc] =
                        f2bf(v / (1.f + expf(-v)));
                }
            }
        }
    }
}

// ---------------------------------------------------------------------------
// Depthwise causal conv (K=4) + bias + SiLU, 4 channels per thread (float4).
// ---------------------------------------------------------------------------
__global__ __launch_bounds__(256) void conv_silu(const float* __restrict__ xcraw,
                                                 const float* __restrict__ w,
                                                 const float* __restrict__ bias,
                                                 float* __restrict__ xc,
                                                 unsigned short* __restrict__ xcb)
{
    const int i4 = blockIdx.x * blockDim.x + threadIdx.x;  // ML*DIMD/4
    if (i4 >= ML * DIMD / 4) return;
    const int dq = i4 & (DIMD / 4 - 1);    // d/4
    const int bl = i4 >> 8;                // b*L + l
    const int l  = bl & (LL - 1);

    const float4 wq0 = ((const float4*)w)[dq * 4 + 0];
    const float4 wq1 = ((const float4*)w)[dq * 4 + 1];
    const float4 wq2 = ((const float4*)w)[dq * 4 + 2];
    const float4 wq3 = ((const float4*)w)[dq * 4 + 3];
    const float4 bv  = ((const float4*)bias)[dq];

    const float* p = xcraw + (size_t)bl * DIMD + dq * 4;
    const float4 z4 = make_float4(0.f, 0.f, 0.f, 0.f);
    const float4 x0 = (l >= 3) ? *(const float4*)(p - 3 * DIMD) : z4;
    const float4 x1 = (l >= 2) ? *(const float4*)(p - 2 * DIMD) : z4;
    const float4 x2 = (l >= 1) ? *(const float4*)(p - 1 * DIMD) : z4;
    const float4 x3 = *(const float4*)p;

    float4 a;
    a.x = bv.x + wq0.x*x0.x + wq0.y*x1.x + wq0.z*x2.x + wq0.w*x3.x;
    a.y = bv.y + wq1.x*x0.y + wq1.y*x1.y + wq1.z*x2.y + wq1.w*x3.y;
    a.z = bv.z + wq2.x*x0.z + wq2.y*x1.z + wq2.z*x2.z + wq2.w*x3.z;
    a.w = bv.w + wq3.x*x0.w + wq3.y*x1.w + wq3.z*x2.w + wq3.w*x3.w;

    float4 v;
    v.x = a.x / (1.f + expf(-a.x));
    v.y = a.y / (1.f + expf(-a.y));
    v.z = a.z / (1.f + expf(-a.z));
    v.w = a.w / (1.f + expf(-a.w));

    ((float4*)xc)[i4] = v;
    ushort4 o;
    o.x = f2bf(v.x); o.y = f2bf(v.y); o.z = f2bf(v.z); o.w = f2bf(v.w);
    ((ushort4*)xcb)[i4] = o;
}

__device__ __forceinline__ float softplus_f(float x) {
    return (x > 20.f) ? x : log1pf(expf(x));
}

// ---------------------------------------------------------------------------
// Scan pass 1: local scan from h=0; emit h[16] + S=sum(dt).
// ---------------------------------------------------------------------------
__global__ __launch_bounds__(256) void scan_part1(const float* __restrict__ xdbl,
                                                  const float* __restrict__ xc,
                                                  float* __restrict__ hfin,
                                                  float* __restrict__ Ssum)
{
    __shared__ float Bsh[LC][NS];   // 1 KB

    const int tid = threadIdx.x;
    const int idx = blockIdx.x * 256 + tid;   // global (b,c,d)
    const int d   = idx & (DIMD - 1);
    const int bc  = idx >> 10;
    const int c   = bc & (NC - 1);
    const int b   = bc >> 7;
    const int l0  = c * LC;

    const float* xdbl_p = xdbl + ((size_t)b * LL + l0) * XD_N;
    const float* xc_p   = xc   + ((size_t)b * LL + l0) * DIMD + d;

    if (tid < LC * NS / 4) {               // 64 threads stage 16x16 B block
        const int l = tid >> 2, q = tid & 3;
        ((float4*)&Bsh[l][0])[q] = ((const float4*)(xdbl_p + (size_t)l * XD_N))[q];
    }
    __syncthreads();

    float raw[LC], xcv[LC];
    #pragma unroll
    for (int i = 0; i < LC; ++i) raw[i] = xdbl_p[(size_t)i * XD_N + 2 * NS + d];
    #pragma unroll
    for (int i = 0; i < LC; ++i) xcv[i] = xc_p[(size_t)i * DIMD];

    float e[LC], dx[LC];
    float S = 0.f;
    #pragma unroll
    for (int i = 0; i < LC; ++i) {
        const float dt = softplus_f(raw[i]);
        S += dt;
        e[i]  = expf(-dt);
        dx[i] = dt * xcv[i];
    }

    float h[NS];
    #pragma unroll
    for (int n = 0; n < NS; ++n) h[n] = 0.f;

    #pragma unroll
    for (int i = 0; i < LC; ++i) {
        const float4* BC = (const float4*)&Bsh[i][0];
        const float4 B0 = BC[0], B1 = BC[1], B2 = BC[2], B3 = BC[3];
        const float ev = e[i], dxv = dx[i];
        const float e2 = ev * ev, e4 = e2 * e2;
        float p0 = ev, p1 = e2, p2 = e2 * ev, p3 = e4;
        h[0]  = fmaf(h[0],  p0, dxv * B0.x);
        h[1]  = fmaf(h[1],  p1, dxv * B0.y);
        h[2]  = fmaf(h[2],  p2, dxv * B0.z);
        h[3]  = fmaf(h[3],  p3, dxv * B0.w);
        p0 *= e4; p1 *= e4; p2 *= e4; p3 *= e4;
        h[4]  = fmaf(h[4],  p0, dxv * B1.x);
        h[5]  = fmaf(h[5],  p1, dxv * B1.y);
        h[6]  = fmaf(h[6],  p2, dxv * B1.z);
        h[7]  = fmaf(h[7],  p3, dxv * B1.w);
        p0 *= e4; p1 *= e4; p2 *= e4; p3 *= e4;
        h[8]  = fmaf(h[8],  p0, dxv * B2.x);
        h[9]  = fmaf(h[9],  p1, dxv * B2.y);
        h[10] = fmaf(h[10], p2, dxv * B2.z);
        h[11] = fmaf(h[11], p3, dxv * B2.w);
        p0 *= e4; p1 *= e4; p2 *= e4; p3 *= e4;
        h[12] = fmaf(h[12], p0, dxv * B3.x);
        h[13] = fmaf(h[13], p1, dxv * B3.y);
        h[14] = fmaf(h[14], p2, dxv * B3.z);
        h[15] = fmaf(h[15], p3, dxv * B3.w);
    }

    float4* hf = (float4*)(hfin + (size_t)idx * NS);
    #pragma unroll
    for (int n = 0; n < 4; ++n) hf[n] = ((float4*)h)[n];
    Ssum[idx] = S;
}

// ---------------------------------------------------------------------------
// Scan pass 2: batched 8-wide prefetch + off-chain expf; hfin rewritten in
// place to carry-in states.
// ---------------------------------------------------------------------------
__global__ __launch_bounds__(256) void scan_combine(float* __restrict__ hfin,
                                                    const float* __restrict__ Ssum)
{
    const int idx = blockIdx.x * blockDim.x + threadIdx.x;  // B*DIMD*NS
    const int n = idx & (NS - 1);
    const int d = (idx >> 4) & (DIMD - 1);
    const int b = idx >> 14;
    const float np1 = (float)(n + 1);

    float hc = 0.f;
    for (int c0 = 0; c0 < NC; c0 += 8) {
        float Sb[8], hb[8], eb[8];
        #pragma unroll
        for (int j = 0; j < 8; ++j) {
            const size_t base = ((size_t)(b * NC + c0 + j) * DIMD + d);
            Sb[j] = Ssum[base];
            hb[j] = hfin[base * NS + n];
        }
        #pragma unroll
        for (int j = 0; j < 8; ++j) eb[j] = expf(-Sb[j] * np1);
        #pragma unroll
        for (int j = 0; j < 8; ++j) {
            const size_t o = ((size_t)(b * NC + c0 + j) * DIMD + d) * NS + n;
            hfin[o] = hc;
            hc = fmaf(hc, eb[j], hb[j]);
        }
    }
}

// ---------------------------------------------------------------------------
// Scan pass 3: seeded re-scan + y + D*xc + z-gate + bf16 store.
// ---------------------------------------------------------------------------
__global__ __launch_bounds__(256) void scan_part2(const float* __restrict__ xdbl,
                                                  const float* __restrict__ xc,
                                                  const unsigned short* __restrict__ zb,
                                                  const float* __restrict__ hfin,
                                                  const float* __restrict__ Dp,
                                                  unsigned short* __restrict__ yout)
{
    __shared__ float BCs[LC][2 * NS];   // 2 KB

    const int tid = threadIdx.x;
    const int idx = blockIdx.x * 256 + tid;
    const int d   = idx & (DIMD - 1);
    const int bc  = idx >> 10;
    const int c   = bc & (NC - 1);
    const int b   = bc >> 7;
    const int l0  = c * LC;

    const float* xdbl_p = xdbl + ((size_t)b * LL + l0) * XD_N;
    const float* xc_p   = xc   + ((size_t)b * LL + l0) * DIMD + d;
    const unsigned short* zb_p = zb + ((size_t)b * LL + l0) * DIMD + d;
    unsigned short* y_p = yout + ((size_t)b * LL + l0) * DIMD + d;

    if (tid < LC * 2 * NS / 4) {
        const int l = tid >> 3, q = tid & 7;
        ((float4*)&BCs[l][0])[q] = ((const float4*)(xdbl_p + (size_t)l * XD_N))[q];
    }
    __syncthreads();

    float raw[LC], xcv[LC], zg[LC];
    #pragma unroll
    for (int i = 0; i < LC; ++i) raw[i] = xdbl_p[(size_t)i * XD_N + 2 * NS + d];
    #pragma unroll
    for (int i = 0; i < LC; ++i) xcv[i] = xc_p[(size_t)i * DIMD];
    #pragma unroll
    for (int i = 0; i < LC; ++i) zg[i] = bf2f(zb_p[(size_t)i * DIMD]);

    float e[LC], dx[LC];
    #pragma unroll
    for (int i = 0; i < LC; ++i) {
        const float dt = softplus_f(raw[i]);
        e[i]  = expf(-dt);
        dx[i] = dt * xcv[i];
    }

    const float Dv = Dp[d];
    float h[NS];
    {
        const float4* hf = (const float4*)(hfin + (size_t)idx * NS);
        #pragma unroll
        for (int n = 0; n < 4; ++n) ((float4*)h)[n] = hf[n];
    }

    #pragma unroll
    for (int i = 0; i < LC; ++i) {
        const float4* BC = (const float4*)&BCs[i][0];
        const float4 B0 = BC[0], B1 = BC[1], B2 = BC[2], B3 = BC[3];
        const float4 C0 = BC[4], C1 = BC[5], C2 = BC[6], C3 = BC[7];
        const float ev = e[i], dxv = dx[i];
        const float e2 = ev * ev, e4 = e2 * e2;
        float p0 = ev, p1 = e2, p2 = e2 * ev, p3 = e4;
        float y0, y1, y2, y3;
        h[0]  = fmaf(h[0],  p0, dxv * B0.x); y0 = h[0]  * C0.x;
        h[1]  = fmaf(h[1],  p1, dxv * B0.y); y1 = h[1]  * C0.y;
        h[2]  = fmaf(h[2],  p2, dxv * B0.z); y2 = h[2]  * C0.z;
        h[3]  = fmaf(h[3],  p3, dxv * B0.w); y3 = h[3]  * C0.w;
        p0 *= e4; p1 *= e4; p2 *= e4; p3 *= e4;
        h[4]  = fmaf(h[4],  p0, dxv * B1.x); y0 = fmaf(h[4],  C1.x, y0);
        h[5]  = fmaf(h[5],  p1, dxv * B1.y); y1 = fmaf(h[5],  C1.y, y1);
        h[6]  = fmaf(h[6],  p2, dxv * B1.z); y2 = fmaf(h[6],  C1.z, y2);
        h[7]  = fmaf(h[7],  p3, dxv * B1.w); y3 = fmaf(h[7],  C1.w, y3);
        p0 *= e4; p1 *= e4; p2 *= e4; p3 *= e4;
        h[8]  = fmaf(h[8],  p0, dxv * B2.x); y0 = fmaf(h[8],  C2.x, y0);
        h[9]  = fmaf(h[9],  p1, dxv * B2.y); y1 = fmaf(h[9],  C2.y, y1);
        h[10] = fmaf(h[10], p2, dxv * B2.z); y2 = fmaf(h[10], C2.z, y2);
        h[11] = fmaf(h[11], p3, dxv * B2.w); y3 = fmaf(h[11], C2.w, y3);
        p0 *= e4; p1 *= e4; p2 *= e4; p3 *= e4;
        h[12] = fmaf(h[12], p0, dxv * B3.x); y0 = fmaf(h[12], C3.x, y0);
        h[13] = fmaf(h[13], p1, dxv * B3.y); y1 = fmaf(h[13], C3.y, y1);
        h[14] = fmaf(h[14], p2, dxv * B3.z); y2 = fmaf(h[14], C3.z, y2);
        h[15] = fmaf(h[15], p3, dxv * B3.w); y3 = fmaf(h[15], C3.w, y3);

        const float y  = (y0 + y1) + (y2 + y3);
        const float yv = fmaf(Dv, xcv[i], y);
        y_p[(size_t)i * DIMD] = f2bf(yv * zg[i]);
    }
}

extern "C" void kernel_launch(void* const* d_in, const int* in_sizes, int n_in,
                              void* d_out, int out_size, void* d_ws, size_t ws_size,
                              hipStream_t stream)
{
    const float* x          = (const float*)d_in[0];
    const float* in_proj_w  = (const float*)d_in[1];
    const float* conv_w     = (const float*)d_in[2];
    const float* conv_b     = (const float*)d_in[3];
    const float* x_proj_w   = (const float*)d_in[4];
    const float* D_param    = (const float*)d_in[5];
    const float* out_proj_w = (const float*)d_in[6];
    float* out = (float*)d_out;

    // workspace layout (~84.5 MiB)
    float* xcraw = (float*)d_ws;                              // ML*DIMD f32
    float* xc    = xcraw + (size_t)ML * DIMD;                 // ML*DIMD f32
    float* xdbl  = xc    + (size_t)ML * DIMD;                 // ML*XD_N f32
    unsigned short* zb  = (unsigned short*)(xdbl + (size_t)ML * XD_N); // ML*DIMD bf16
    unsigned short* xb  = zb  + (size_t)ML * DIMD;            // ML*DIMD bf16
    unsigned short* xcb = xb  + (size_t)ML * DIMD;            // ML*DIMD bf16
    unsigned short* wb1 = xcb + (size_t)ML * DIMD;            // XZ_N*DIMD bf16
    unsigned short* wb2 = wb1 + (size_t)XZ_N * DIMD;          // XD_N*DIMD bf16
    unsigned short* wb3 = wb2 + (size_t)XD_N * DIMD;          // DIMD*DIMD bf16
    unsigned short* yb  = xb;    // xb dead after GEMM1; reuse for scan output

    // hfin: B*NC*DIMD*NS floats = 16.8 MB = exact fit in d_out (dead till GEMM3)
    float* hfin = out;
    // Ssum: 1 MB, aliases wb1 (dead after GEMM1; scan runs after GEMM2)
    float* Ssum = (float*)wb1;

    const int n0 = ML * DIMD / 4, n1 = XZ_N * DIMD / 4,
              n2 = XD_N * DIMD / 4, n3 = DIMD * DIMD / 4;
    const int ncvt = n0 + n1 + n2 + n3;

    // 0) all f32->bf16 conversions in one launch
    cvt_all<<<(ncvt + 255) / 256, 256, 0, stream>>>(
        x, xb, n0, in_proj_w, wb1, n1, x_proj_w, wb2, n2, out_proj_w, wb3, n3);

    // 1) xz = x @ in_proj_w.T; x_c half -> f32 xcraw, z half -> silu bf16 zb
    gemm_mfma_bt<<<dim3(XZ_N / 128, ML / 128), 256, 0, stream>>>(
        xb, wb1, xcraw, zb, ML, XZ_N, DIMD, DIMD);

    // 2) depthwise conv + bias + silu -> xc (f32) + xcb (bf16)
    conv_silu<<<(ML * DIMD / 4) / 256, 256, 0, stream>>>(
        xcraw, conv_w, conv_b, xc, xcb);

    // 3) x_dbl = xc @ x_proj_w.T     (4096 x 1056 x 1024)
    gemm_mfma_bt<<<dim3((XD_N + 127) / 128, ML / 128), 256, 0, stream>>>(
        xcb, wb2, xdbl, nullptr, ML, XD_N, DIMD, XD_N);

    // 4) chunked selective scan — 3-kernel path. NOTE: do NOT fuse with
    //    grid.sync on this chip: R9 measured 465us vs ~75us for these three
    //    (grid-wide sync forces per-XCD L2 writeback+invalidate -> 577 MB HBM).
    scan_part1<<<(BB * NC * DIMD) / 256, 256, 0, stream>>>(xdbl, xc, hfin, Ssum);
    scan_combine<<<(BB * DIMD * NS) / 256, 256, 0, stream>>>(hfin, Ssum);
    scan_part2<<<(BB * NC * DIMD) / 256, 256, 0, stream>>>(xdbl, xc, zb, hfin,
                                                           D_param, yb);

    // 5) out = y @ out_proj_w.T      (4096 x 1024 x 1024)
    gemm_mfma_bt<<<dim3(DIMD / 128, ML / 128), 256, 0, stream>>>(
        yb, wb3, out, nullptr, ML, DIMD, DIMD, DIMD);
}

// Round 11
// 246.250 us; speedup vs baseline: 2.7294x; 1.0182x over previous
//
#include <hip/hip_runtime.h>
#include <cmath>

#define BB   2
#define LL   2048
#define DIMD 1024
#define NS   16
#define KC   4
#define ML   (BB*LL)        // 4096 rows (B*L)
#define XZ_N (2*DIMD)       // 2048
#define XD_N (2*NS + DIMD)  // 1056
#define LC   8              // scan chunk length (8 -> 2048 scan blocks)
#define NC   (LL/LC)        // 256 chunks per sequence

typedef __attribute__((ext_vector_type(8))) short bf16x8;   // 8 bf16 (4 VGPRs)
typedef __attribute__((ext_vector_type(4))) float f32x4;    // MFMA acc

__device__ __forceinline__ unsigned short f2bf(float f) {
    union { float f; unsigned u; } v; v.f = f;
    unsigned r = v.u + 0x7FFF + ((v.u >> 16) & 1);   // round-to-nearest-even
    return (unsigned short)(r >> 16);
}
__device__ __forceinline__ float bf2f(unsigned short u) {
    union { unsigned u; float f; } v; v.u = (unsigned)u << 16;
    return v.f;
}

// ---------------------------------------------------------------------------
// Fused f32 -> bf16 conversion for x + the 3 weight matrices (one launch).
// ---------------------------------------------------------------------------
__global__ __launch_bounds__(256) void cvt_all(
    const float* __restrict__ s0, unsigned short* __restrict__ d0, int n0,
    const float* __restrict__ s1, unsigned short* __restrict__ d1, int n1,
    const float* __restrict__ s2, unsigned short* __restrict__ d2, int n2,
    const float* __restrict__ s3, unsigned short* __restrict__ d3, int n3)
{
    int i = blockIdx.x * blockDim.x + threadIdx.x;
    const float* src; unsigned short* dst;
    if (i < n0)                { src = s0; dst = d0; }
    else if ((i -= n0) < n1)   { src = s1; dst = d1; }
    else if ((i -= n1) < n2)   { src = s2; dst = d2; }
    else if ((i -= n2) < n3)   { src = s3; dst = d3; }
    else return;
    float4 f = ((const float4*)src)[i];
    ushort4 o;
    o.x = f2bf(f.x); o.y = f2bf(f.y); o.z = f2bf(f.z); o.w = f2bf(f.w);
    ((ushort4*)dst)[i] = o;
}

// ---------------------------------------------------------------------------
// bf16 MFMA GEMM, C = A[M,K] @ W[N,K]^T. 128x64 tile, BK=64, 4 waves stacked
// vertically (wave w: rows w*32..w*32+31, all 64 cols), acc[2][4] of
// mfma_f32_16x16x32_bf16. global_load_lds w=16, XOR-8 swizzle (slot s of row
// r holds global chunk s^(r&7)). 128x64 (vs 128x128) doubles the grid:
// gemm1=1024, gemm2=544, gemm3=512 blocks -> 2-4 blocks/CU for wave overlap.
// Epilogue: cols < nsplit -> f32 (row stride nsplit); else silu+bf16 to zb.
// ---------------------------------------------------------------------------
__global__ __launch_bounds__(256) void gemm_mfma_bt(
    const unsigned short* __restrict__ A,
    const unsigned short* __restrict__ Bw,
    float* __restrict__ C,
    unsigned short* __restrict__ zb,
    int M, int N, int K, int nsplit)
{
    __shared__ short As[128 * 64];   // 16 KB
    __shared__ short Bs[64 * 64];    //  8 KB

    const int tid  = threadIdx.x;
    const int lane = tid & 63;
    const int wave = tid >> 6;
    const int bm = blockIdx.y * 128;
    const int bn = blockIdx.x * 64;
    const int wm = wave * 32;
    const int l15  = lane & 15;
    const int quad = lane >> 4;

    f32x4 acc[2][4];
    #pragma unroll
    for (int i = 0; i < 2; ++i)
        #pragma unroll
        for (int j = 0; j < 4; ++j)
            acc[i][j] = (f32x4){0.f, 0.f, 0.f, 0.f};

    for (int k0 = 0; k0 < K; k0 += 64) {
        __syncthreads();
        // stage A: 128 rows x 8 chunks = 1024 chunks, 4 iters of 256
        #pragma unroll
        for (int q = 0; q < 4; ++q) {
            const int ci = q * 256 + tid;
            const int r  = ci >> 3;
            const int cc = (ci & 7) ^ (r & 7);
            short* ldsA = As + (size_t)(q * 256 + (tid & ~63)) * 8;
            const unsigned short* ga = A + (size_t)(bm + r) * K + k0 + cc * 8;
            __builtin_amdgcn_global_load_lds(
                (const __attribute__((address_space(1))) void*)ga,
                (__attribute__((address_space(3))) void*)ldsA, 16, 0, 0);
        }
        // stage B: 64 rows x 8 chunks = 512 chunks, 2 iters of 256
        #pragma unroll
        for (int q = 0; q < 2; ++q) {
            const int ci = q * 256 + tid;
            const int r  = ci >> 3;
            const int cc = (ci & 7) ^ (r & 7);
            short* ldsB = Bs + (size_t)(q * 256 + (tid & ~63)) * 8;
            int rb = bn + r; if (rb > N - 1) rb = N - 1;
            const unsigned short* gb = Bw + (size_t)rb * K + k0 + cc * 8;
            __builtin_amdgcn_global_load_lds(
                (const __attribute__((address_space(1))) void*)gb,
                (__attribute__((address_space(3))) void*)ldsB, 16, 0, 0);
        }
        __syncthreads();

        #pragma unroll
        for (int kh = 0; kh < 2; ++kh) {
            bf16x8 af[2], bfr[4];
            #pragma unroll
            for (int i = 0; i < 2; ++i) {
                const int row = wm + i * 16 + l15;
                const int pc  = (kh * 4 + quad) ^ (row & 7);
                af[i] = *(const bf16x8*)(As + row * 64 + pc * 8);
            }
            #pragma unroll
            for (int j = 0; j < 4; ++j) {
                const int row = j * 16 + l15;
                const int pc  = (kh * 4 + quad) ^ (row & 7);
                bfr[j] = *(const bf16x8*)(Bs + row * 64 + pc * 8);
            }
            #pragma unroll
            for (int i = 0; i < 2; ++i)
                #pragma unroll
                for (int j = 0; j < 4; ++j)
                    acc[i][j] = __builtin_amdgcn_mfma_f32_16x16x32_bf16(
                        af[i], bfr[j], acc[i][j], 0, 0, 0);
        }
    }

    #pragma unroll
    for (int i = 0; i < 2; ++i) {
        const int rbase = bm + wm + i * 16 + quad * 4;
        #pragma unroll
        for (int j = 0; j < 4; ++j) {
            const int col = bn + j * 16 + l15;
            if (col < nsplit) {
                #pragma unroll
                for (int r = 0; r < 4; ++r)
                    C[(size_t)(rbase + r) * nsplit + col] = acc[i][j][r];
            } else if (col < N) {
                const int zc = col - nsplit;
                #pragma unroll
                for (int r = 0; r < 4; ++r) {
                    const float v = acc[i][j][r];
                    zb[(size_t)(rbase + r) * DIMD + zc] =
                        f2bf(v / (1.f + expf(-v)));
                }
            }
        }
    }
}

// ---------------------------------------------------------------------------
// Depthwise causal conv (K=4) + bias + SiLU, 4 channels per thread (float4).
// ---------------------------------------------------------------------------
__global__ __launch_bounds__(256) void conv_silu(const float* __restrict__ xcraw,
                                                 const float* __restrict__ w,
                                                 const float* __restrict__ bias,
                                                 float* __restrict__ xc,
                                                 unsigned short* __restrict__ xcb)
{
    const int i4 = blockIdx.x * blockDim.x + threadIdx.x;  // ML*DIMD/4
    if (i4 >= ML * DIMD / 4) return;
    const int dq = i4 & (DIMD / 4 - 1);    // d/4
    const int bl = i4 >> 8;                // b*L + l
    const int l  = bl & (LL - 1);

    const float4 wq0 = ((const float4*)w)[dq * 4 + 0];
    const float4 wq1 = ((const float4*)w)[dq * 4 + 1];
    const float4 wq2 = ((const float4*)w)[dq * 4 + 2];
    const float4 wq3 = ((const float4*)w)[dq * 4 + 3];
    const float4 bv  = ((const float4*)bias)[dq];

    const float* p = xcraw + (size_t)bl * DIMD + dq * 4;
    const float4 z4 = make_float4(0.f, 0.f, 0.f, 0.f);
    const float4 x0 = (l >= 3) ? *(const float4*)(p - 3 * DIMD) : z4;
    const float4 x1 = (l >= 2) ? *(const float4*)(p - 2 * DIMD) : z4;
    const float4 x2 = (l >= 1) ? *(const float4*)(p - 1 * DIMD) : z4;
    const float4 x3 = *(const float4*)p;

    float4 a;
    a.x = bv.x + wq0.x*x0.x + wq0.y*x1.x + wq0.z*x2.x + wq0.w*x3.x;
    a.y = bv.y + wq1.x*x0.y + wq1.y*x1.y + wq1.z*x2.y + wq1.w*x3.y;
    a.z = bv.z + wq2.x*x0.z + wq2.y*x1.z + wq2.z*x2.z + wq2.w*x3.z;
    a.w = bv.w + wq3.x*x0.w + wq3.y*x1.w + wq3.z*x2.w + wq3.w*x3.w;

    float4 v;
    v.x = a.x / (1.f + expf(-a.x));
    v.y = a.y / (1.f + expf(-a.y));
    v.z = a.z / (1.f + expf(-a.z));
    v.w = a.w / (1.f + expf(-a.w));

    ((float4*)xc)[i4] = v;
    ushort4 o;
    o.x = f2bf(v.x); o.y = f2bf(v.y); o.z = f2bf(v.z); o.w = f2bf(v.w);
    ((ushort4*)xcb)[i4] = o;
}

__device__ __forceinline__ float softplus_f(float x) {
    return (x > 20.f) ? x : log1pf(expf(x));
}

// ---------------------------------------------------------------------------
// Scan pass 1 (LC=8): local scan from h=0; emit h[16] + S=sum(dt).
// 2048 blocks -> ~6-8 waves/SIMD for latency hiding.
// ---------------------------------------------------------------------------
__global__ __launch_bounds__(256) void scan_part1(const float* __restrict__ xdbl,
                                                  const float* __restrict__ xc,
                                                  float* __restrict__ hfin,
                                                  float* __restrict__ Ssum)
{
    __shared__ float Bsh[LC][NS];   // 512 B

    const int tid = threadIdx.x;
    const int idx = blockIdx.x * 256 + tid;   // (b, c, d)
    const int d   = idx & (DIMD - 1);
    const int bc  = idx >> 10;
    const int c   = bc & (NC - 1);
    const int b   = bc / NC;
    const int l0  = c * LC;

    const float* xdbl_p = xdbl + ((size_t)b * LL + l0) * XD_N;
    const float* xc_p   = xc   + ((size_t)b * LL + l0) * DIMD + d;

    if (tid < LC * NS / 4) {               // 32 threads stage 8x16 B block
        const int l = tid >> 2, q = tid & 3;
        ((float4*)&Bsh[l][0])[q] = ((const float4*)(xdbl_p + (size_t)l * XD_N))[q];
    }
    __syncthreads();

    float raw[LC], xcv[LC];
    #pragma unroll
    for (int i = 0; i < LC; ++i) raw[i] = xdbl_p[(size_t)i * XD_N + 2 * NS + d];
    #pragma unroll
    for (int i = 0; i < LC; ++i) xcv[i] = xc_p[(size_t)i * DIMD];

    float e[LC], dx[LC];
    float S = 0.f;
    #pragma unroll
    for (int i = 0; i < LC; ++i) {
        const float dt = softplus_f(raw[i]);
        S += dt;
        e[i]  = expf(-dt);
        dx[i] = dt * xcv[i];
    }

    float h[NS];
    #pragma unroll
    for (int n = 0; n < NS; ++n) h[n] = 0.f;

    #pragma unroll
    for (int i = 0; i < LC; ++i) {
        const float4* BC = (const float4*)&Bsh[i][0];
        const float4 B0 = BC[0], B1 = BC[1], B2 = BC[2], B3 = BC[3];
        const float ev = e[i], dxv = dx[i];
        const float e2 = ev * ev, e4 = e2 * e2;
        float p0 = ev, p1 = e2, p2 = e2 * ev, p3 = e4;
        h[0]  = fmaf(h[0],  p0, dxv * B0.x);
        h[1]  = fmaf(h[1],  p1, dxv * B0.y);
        h[2]  = fmaf(h[2],  p2, dxv * B0.z);
        h[3]  = fmaf(h[3],  p3, dxv * B0.w);
        p0 *= e4; p1 *= e4; p2 *= e4; p3 *= e4;
        h[4]  = fmaf(h[4],  p0, dxv * B1.x);
        h[5]  = fmaf(h[5],  p1, dxv * B1.y);
        h[6]  = fmaf(h[6],  p2, dxv * B1.z);
        h[7]  = fmaf(h[7],  p3, dxv * B1.w);
        p0 *= e4; p1 *= e4; p2 *= e4; p3 *= e4;
        h[8]  = fmaf(h[8],  p0, dxv * B2.x);
        h[9]  = fmaf(h[9],  p1, dxv * B2.y);
        h[10] = fmaf(h[10], p2, dxv * B2.z);
        h[11] = fmaf(h[11], p3, dxv * B2.w);
        p0 *= e4; p1 *= e4; p2 *= e4; p3 *= e4;
        h[12] = fmaf(h[12], p0, dxv * B3.x);
        h[13] = fmaf(h[13], p1, dxv * B3.y);
        h[14] = fmaf(h[14], p2, dxv * B3.z);
        h[15] = fmaf(h[15], p3, dxv * B3.w);
    }

    float4* hf = (float4*)(hfin + (size_t)idx * NS);
    #pragma unroll
    for (int n = 0; n < 4; ++n) hf[n] = ((float4*)h)[n];
    Ssum[idx] = S;
}

// ---------------------------------------------------------------------------
// Scan pass 2: batched 8-wide prefetch + off-chain expf over NC=256 chunks;
// hfin rewritten in place to carry-in states.
// ---------------------------------------------------------------------------
__global__ __launch_bounds__(256) void scan_combine(float* __restrict__ hfin,
                                                    const float* __restrict__ Ssum)
{
    const int idx = blockIdx.x * blockDim.x + threadIdx.x;  // B*DIMD*NS
    const int n = idx & (NS - 1);
    const int d = (idx >> 4) & (DIMD - 1);
    const int b = idx >> 14;
    const float np1 = (float)(n + 1);

    float hc = 0.f;
    for (int c0 = 0; c0 < NC; c0 += 8) {
        float Sb[8], hb[8], eb[8];
        #pragma unroll
        for (int j = 0; j < 8; ++j) {
            const size_t base = ((size_t)(b * NC + c0 + j) * DIMD + d);
            Sb[j] = Ssum[base];
            hb[j] = hfin[base * NS + n];
        }
        #pragma unroll
        for (int j = 0; j < 8; ++j) eb[j] = expf(-Sb[j] * np1);
        #pragma unroll
        for (int j = 0; j < 8; ++j) {
            const size_t o = ((size_t)(b * NC + c0 + j) * DIMD + d) * NS + n;
            hfin[o] = hc;
            hc = fmaf(hc, eb[j], hb[j]);
        }
    }
}

// ---------------------------------------------------------------------------
// Scan pass 3 (LC=8): seeded re-scan + y + D*xc + z-gate + bf16 store.
// ---------------------------------------------------------------------------
__global__ __launch_bounds__(256) void scan_part2(const float* __restrict__ xdbl,
                                                  const float* __restrict__ xc,
                                                  const unsigned short* __restrict__ zb,
                                                  const float* __restrict__ hfin,
                                                  const float* __restrict__ Dp,
                                                  unsigned short* __restrict__ yout)
{
    __shared__ float BCs[LC][2 * NS];   // 1 KB

    const int tid = threadIdx.x;
    const int idx = blockIdx.x * 256 + tid;
    const int d   = idx & (DIMD - 1);
    const int bc  = idx >> 10;
    const int c   = bc & (NC - 1);
    const int b   = bc / NC;
    const int l0  = c * LC;

    const float* xdbl_p = xdbl + ((size_t)b * LL + l0) * XD_N;
    const float* xc_p   = xc   + ((size_t)b * LL + l0) * DIMD + d;
    const unsigned short* zb_p = zb + ((size_t)b * LL + l0) * DIMD + d;
    unsigned short* y_p = yout + ((size_t)b * LL + l0) * DIMD + d;

    if (tid < LC * 2 * NS / 4) {           // 64 threads stage 8x32 B|C block
        const int l = tid >> 3, q = tid & 7;
        ((float4*)&BCs[l][0])[q] = ((const float4*)(xdbl_p + (size_t)l * XD_N))[q];
    }
    __syncthreads();

    float raw[LC], xcv[LC], zg[LC];
    #pragma unroll
    for (int i = 0; i < LC; ++i) raw[i] = xdbl_p[(size_t)i * XD_N + 2 * NS + d];
    #pragma unroll
    for (int i = 0; i < LC; ++i) xcv[i] = xc_p[(size_t)i * DIMD];
    #pragma unroll
    for (int i = 0; i < LC; ++i) zg[i] = bf2f(zb_p[(size_t)i * DIMD]);

    float e[LC], dx[LC];
    #pragma unroll
    for (int i = 0; i < LC; ++i) {
        const float dt = softplus_f(raw[i]);
        e[i]  = expf(-dt);
        dx[i] = dt * xcv[i];
    }

    const float Dv = Dp[d];
    float h[NS];
    {
        const float4* hf = (const float4*)(hfin + (size_t)idx * NS);
        #pragma unroll
        for (int n = 0; n < 4; ++n) ((float4*)h)[n] = hf[n];
    }

    #pragma unroll
    for (int i = 0; i < LC; ++i) {
        const float4* BC = (const float4*)&BCs[i][0];
        const float4 B0 = BC[0], B1 = BC[1], B2 = BC[2], B3 = BC[3];
        const float4 C0 = BC[4], C1 = BC[5], C2 = BC[6], C3 = BC[7];
        const float ev = e[i], dxv = dx[i];
        const float e2 = ev * ev, e4 = e2 * e2;
        float p0 = ev, p1 = e2, p2 = e2 * ev, p3 = e4;
        float y0, y1, y2, y3;
        h[0]  = fmaf(h[0],  p0, dxv * B0.x); y0 = h[0]  * C0.x;
        h[1]  = fmaf(h[1],  p1, dxv * B0.y); y1 = h[1]  * C0.y;
        h[2]  = fmaf(h[2],  p2, dxv * B0.z); y2 = h[2]  * C0.z;
        h[3]  = fmaf(h[3],  p3, dxv * B0.w); y3 = h[3]  * C0.w;
        p0 *= e4; p1 *= e4; p2 *= e4; p3 *= e4;
        h[4]  = fmaf(h[4],  p0, dxv * B1.x); y0 = fmaf(h[4],  C1.x, y0);
        h[5]  = fmaf(h[5],  p1, dxv * B1.y); y1 = fmaf(h[5],  C1.y, y1);
        h[6]  = fmaf(h[6],  p2, dxv * B1.z); y2 = fmaf(h[6],  C1.z, y2);
        h[7]  = fmaf(h[7],  p3, dxv * B1.w); y3 = fmaf(h[7],  C1.w, y3);
        p0 *= e4; p1 *= e4; p2 *= e4; p3 *= e4;
        h[8]  = fmaf(h[8],  p0, dxv * B2.x); y0 = fmaf(h[8],  C2.x, y0);
        h[9]  = fmaf(h[9],  p1, dxv * B2.y); y1 = fmaf(h[9],  C2.y, y1);
        h[10] = fmaf(h[10], p2, dxv * B2.z); y2 = fmaf(h[10], C2.z, y2);
        h[11] = fmaf(h[11], p3, dxv * B2.w); y3 = fmaf(h[11], C2.w, y3);
        p0 *= e4; p1 *= e4; p2 *= e4; p3 *= e4;
        h[12] = fmaf(h[12], p0, dxv * B3.x); y0 = fmaf(h[12], C3.x, y0);
        h[13] = fmaf(h[13], p1, dxv * B3.y); y1 = fmaf(h[13], C3.y, y1);
        h[14] = fmaf(h[14], p2, dxv * B3.z); y2 = fmaf(h[14], C3.z, y2);
        h[15] = fmaf(h[15], p3, dxv * B3.w); y3 = fmaf(h[15], C3.w, y3);

        const float y  = (y0 + y1) + (y2 + y3);
        const float yv = fmaf(Dv, xcv[i], y);
        y_p[(size_t)i * DIMD] = f2bf(yv * zg[i]);
    }
}

extern "C" void kernel_launch(void* const* d_in, const int* in_sizes, int n_in,
                              void* d_out, int out_size, void* d_ws, size_t ws_size,
                              hipStream_t stream)
{
    const float* x          = (const float*)d_in[0];
    const float* in_proj_w  = (const float*)d_in[1];
    const float* conv_w     = (const float*)d_in[2];
    const float* conv_b     = (const float*)d_in[3];
    const float* x_proj_w   = (const float*)d_in[4];
    const float* D_param    = (const float*)d_in[5];
    const float* out_proj_w = (const float*)d_in[6];
    float* out = (float*)d_out;

    // workspace layout (~120 MiB of the ~268 MiB ws)
    float* xcraw = (float*)d_ws;                              // ML*DIMD f32
    float* xc    = xcraw + (size_t)ML * DIMD;                 // ML*DIMD f32
    float* xdbl  = xc    + (size_t)ML * DIMD;                 // ML*XD_N f32
    unsigned short* zb  = (unsigned short*)(xdbl + (size_t)ML * XD_N); // ML*DIMD bf16
    unsigned short* xb  = zb  + (size_t)ML * DIMD;            // ML*DIMD bf16
    unsigned short* xcb = xb  + (size_t)ML * DIMD;            // ML*DIMD bf16
    unsigned short* wb1 = xcb + (size_t)ML * DIMD;            // XZ_N*DIMD bf16
    unsigned short* wb2 = wb1 + (size_t)XZ_N * DIMD;          // XD_N*DIMD bf16
    unsigned short* wb3 = wb2 + (size_t)XD_N * DIMD;          // DIMD*DIMD bf16
    float* hfin = (float*)(wb3 + (size_t)DIMD * DIMD);        // B*NC*DIMD*NS f32 (33.5 MB)
    float* Ssum = hfin + (size_t)BB * NC * DIMD * NS;         // B*NC*DIMD f32 (2 MB)
    unsigned short* yb  = xb;    // xb dead after GEMM1; reuse for scan output

    const int n0 = ML * DIMD / 4, n1 = XZ_N * DIMD / 4,
              n2 = XD_N * DIMD / 4, n3 = DIMD * DIMD / 4;
    const int ncvt = n0 + n1 + n2 + n3;

    // 0) all f32->bf16 conversions in one launch
    cvt_all<<<(ncvt + 255) / 256, 256, 0, stream>>>(
        x, xb, n0, in_proj_w, wb1, n1, x_proj_w, wb2, n2, out_proj_w, wb3, n3);

    // 1) xz = x @ in_proj_w.T; x_c half -> f32 xcraw, z half -> silu bf16 zb
    gemm_mfma_bt<<<dim3(XZ_N / 64, ML / 128), 256, 0, stream>>>(
        xb, wb1, xcraw, zb, ML, XZ_N, DIMD, DIMD);

    // 2) depthwise conv + bias + silu -> xc (f32) + xcb (bf16)
    conv_silu<<<(ML * DIMD / 4) / 256, 256, 0, stream>>>(
        xcraw, conv_w, conv_b, xc, xcb);

    // 3) x_dbl = xc @ x_proj_w.T     (4096 x 1056 x 1024)
    gemm_mfma_bt<<<dim3((XD_N + 63) / 64, ML / 128), 256, 0, stream>>>(
        xcb, wb2, xdbl, nullptr, ML, XD_N, DIMD, XD_N);

    // 4) chunked selective scan (LC=8 -> 2048 blocks). Do NOT grid.sync-fuse
    //    (R9: grid sync forces per-XCD L2 writeback -> 577 MB HBM, 465 us).
    scan_part1<<<(BB * NC * DIMD) / 256, 256, 0, stream>>>(xdbl, xc, hfin, Ssum);
    scan_combine<<<(BB * DIMD * NS) / 256, 256, 0, stream>>>(hfin, Ssum);
    scan_part2<<<(BB * NC * DIMD) / 256, 256, 0, stream>>>(xdbl, xc, zb, hfin,
                                                           D_param, yb);

    // 5) out = y @ out_proj_w.T      (4096 x 1024 x 1024)
    gemm_mfma_bt<<<dim3(DIMD / 64, ML / 128), 256, 0, stream>>>(
        yb, wb3, out, nullptr, ML, DIMD, DIMD, DIMD);
}

// Round 12
// 214.409 us; speedup vs baseline: 3.1347x; 1.1485x over previous
//
#include <hip/hip_runtime.h>
#include <cmath>

#define BB   2
#define LL   2048
#define DIMD 1024
#define NS   16
#define KC   4
#define ML   (BB*LL)        // 4096 rows (B*L)
#define XZ_N (2*DIMD)       // 2048
#define XD_N (2*NS + DIMD)  // 1056
#define LC   16             // scan chunk length (16 proven best: R7/R10 vs R11)
#define NC   (LL/LC)        // 128 chunks per sequence

typedef __attribute__((ext_vector_type(8))) short bf16x8;   // 8 bf16 (4 VGPRs)
typedef __attribute__((ext_vector_type(4))) float f32x4;    // MFMA acc

__device__ __forceinline__ unsigned short f2bf(float f) {
    union { float f; unsigned u; } v; v.f = f;
    unsigned r = v.u + 0x7FFF + ((v.u >> 16) & 1);   // round-to-nearest-even
    return (unsigned short)(r >> 16);
}
__device__ __forceinline__ float bf2f(unsigned short u) {
    union { unsigned u; float f; } v; v.u = (unsigned)u << 16;
    return v.f;
}
// fast silu via hw exp
__device__ __forceinline__ float silu_f(float a) {
    return a / (1.f + __expf(-a));
}
// e = exp(-softplus(raw)) = sigmoid(-raw)  [algebraic identity];
// dt = softplus(raw) = -log(e), with dt=raw for large raw (log(1+e^x)->x).
__device__ __forceinline__ void dt_decay(float raw, float& dt, float& e) {
    const float t = __expf(fminf(raw, 80.f));
    e  = 1.f / (1.f + t);
    dt = (raw > 15.f) ? raw : -__logf(e);
}

// ---------------------------------------------------------------------------
// Fused f32 -> bf16 conversion for x + the 3 weight matrices (one launch).
// ---------------------------------------------------------------------------
__global__ __launch_bounds__(256) void cvt_all(
    const float* __restrict__ s0, unsigned short* __restrict__ d0, int n0,
    const float* __restrict__ s1, unsigned short* __restrict__ d1, int n1,
    const float* __restrict__ s2, unsigned short* __restrict__ d2, int n2,
    const float* __restrict__ s3, unsigned short* __restrict__ d3, int n3)
{
    int i = blockIdx.x * blockDim.x + threadIdx.x;
    const float* src; unsigned short* dst;
    if (i < n0)                { src = s0; dst = d0; }
    else if ((i -= n0) < n1)   { src = s1; dst = d1; }
    else if ((i -= n1) < n2)   { src = s2; dst = d2; }
    else if ((i -= n2) < n3)   { src = s3; dst = d3; }
    else return;
    float4 f = ((const float4*)src)[i];
    ushort4 o;
    o.x = f2bf(f.x); o.y = f2bf(f.y); o.z = f2bf(f.z); o.w = f2bf(f.w);
    ((ushort4*)dst)[i] = o;
}

// ---------------------------------------------------------------------------
// bf16 MFMA GEMM, C = A[M,K] @ W[N,K]^T. 128x64 tile, BK=64, 4 waves stacked
// vertically, acc[2][4] of mfma_f32_16x16x32_bf16. global_load_lds w=16,
// XOR-8 swizzle. Epilogue: col<nsplit -> f32; else silu+bf16 to zb.
// ---------------------------------------------------------------------------
__global__ __launch_bounds__(256) void gemm_mfma_bt(
    const unsigned short* __restrict__ A,
    const unsigned short* __restrict__ Bw,
    float* __restrict__ C,
    unsigned short* __restrict__ zb,
    int M, int N, int K, int nsplit)
{
    __shared__ short As[128 * 64];   // 16 KB
    __shared__ short Bs[64 * 64];    //  8 KB

    const int tid  = threadIdx.x;
    const int lane = tid & 63;
    const int wave = tid >> 6;
    const int bm = blockIdx.y * 128;
    const int bn = blockIdx.x * 64;
    const int wm = wave * 32;
    const int l15  = lane & 15;
    const int quad = lane >> 4;

    f32x4 acc[2][4];
    #pragma unroll
    for (int i = 0; i < 2; ++i)
        #pragma unroll
        for (int j = 0; j < 4; ++j)
            acc[i][j] = (f32x4){0.f, 0.f, 0.f, 0.f};

    for (int k0 = 0; k0 < K; k0 += 64) {
        __syncthreads();
        #pragma unroll
        for (int q = 0; q < 4; ++q) {
            const int ci = q * 256 + tid;
            const int r  = ci >> 3;
            const int cc = (ci & 7) ^ (r & 7);
            short* ldsA = As + (size_t)(q * 256 + (tid & ~63)) * 8;
            const unsigned short* ga = A + (size_t)(bm + r) * K + k0 + cc * 8;
            __builtin_amdgcn_global_load_lds(
                (const __attribute__((address_space(1))) void*)ga,
                (__attribute__((address_space(3))) void*)ldsA, 16, 0, 0);
        }
        #pragma unroll
        for (int q = 0; q < 2; ++q) {
            const int ci = q * 256 + tid;
            const int r  = ci >> 3;
            const int cc = (ci & 7) ^ (r & 7);
            short* ldsB = Bs + (size_t)(q * 256 + (tid & ~63)) * 8;
            int rb = bn + r; if (rb > N - 1) rb = N - 1;
            const unsigned short* gb = Bw + (size_t)rb * K + k0 + cc * 8;
            __builtin_amdgcn_global_load_lds(
                (const __attribute__((address_space(1))) void*)gb,
                (__attribute__((address_space(3))) void*)ldsB, 16, 0, 0);
        }
        __syncthreads();

        #pragma unroll
        for (int kh = 0; kh < 2; ++kh) {
            bf16x8 af[2], bfr[4];
            #pragma unroll
            for (int i = 0; i < 2; ++i) {
                const int row = wm + i * 16 + l15;
                const int pc  = (kh * 4 + quad) ^ (row & 7);
                af[i] = *(const bf16x8*)(As + row * 64 + pc * 8);
            }
            #pragma unroll
            for (int j = 0; j < 4; ++j) {
                const int row = j * 16 + l15;
                const int pc  = (kh * 4 + quad) ^ (row & 7);
                bfr[j] = *(const bf16x8*)(Bs + row * 64 + pc * 8);
            }
            #pragma unroll
            for (int i = 0; i < 2; ++i)
                #pragma unroll
                for (int j = 0; j < 4; ++j)
                    acc[i][j] = __builtin_amdgcn_mfma_f32_16x16x32_bf16(
                        af[i], bfr[j], acc[i][j], 0, 0, 0);
        }
    }

    #pragma unroll
    for (int i = 0; i < 2; ++i) {
        const int rbase = bm + wm + i * 16 + quad * 4;
        #pragma unroll
        for (int j = 0; j < 4; ++j) {
            const int col = bn + j * 16 + l15;
            if (col < nsplit) {
                #pragma unroll
                for (int r = 0; r < 4; ++r)
                    C[(size_t)(rbase + r) * nsplit + col] = acc[i][j][r];
            } else if (col < N) {
                const int zc = col - nsplit;
                #pragma unroll
                for (int r = 0; r < 4; ++r)
                    zb[(size_t)(rbase + r) * DIMD + zc] = f2bf(silu_f(acc[i][j][r]));
            }
        }
    }
}

// ---------------------------------------------------------------------------
// Depthwise causal conv (K=4) + bias + SiLU, 4 channels per thread (float4).
// ---------------------------------------------------------------------------
__global__ __launch_bounds__(256) void conv_silu(const float* __restrict__ xcraw,
                                                 const float* __restrict__ w,
                                                 const float* __restrict__ bias,
                                                 float* __restrict__ xc,
                                                 unsigned short* __restrict__ xcb)
{
    const int i4 = blockIdx.x * blockDim.x + threadIdx.x;  // ML*DIMD/4
    if (i4 >= ML * DIMD / 4) return;
    const int dq = i4 & (DIMD / 4 - 1);    // d/4
    const int bl = i4 >> 8;                // b*L + l
    const int l  = bl & (LL - 1);

    const float4 wq0 = ((const float4*)w)[dq * 4 + 0];
    const float4 wq1 = ((const float4*)w)[dq * 4 + 1];
    const float4 wq2 = ((const float4*)w)[dq * 4 + 2];
    const float4 wq3 = ((const float4*)w)[dq * 4 + 3];
    const float4 bv  = ((const float4*)bias)[dq];

    const float* p = xcraw + (size_t)bl * DIMD + dq * 4;
    const float4 z4 = make_float4(0.f, 0.f, 0.f, 0.f);
    const float4 x0 = (l >= 3) ? *(const float4*)(p - 3 * DIMD) : z4;
    const float4 x1 = (l >= 2) ? *(const float4*)(p - 2 * DIMD) : z4;
    const float4 x2 = (l >= 1) ? *(const float4*)(p - 1 * DIMD) : z4;
    const float4 x3 = *(const float4*)p;

    float4 a;
    a.x = bv.x + wq0.x*x0.x + wq0.y*x1.x + wq0.z*x2.x + wq0.w*x3.x;
    a.y = bv.y + wq1.x*x0.y + wq1.y*x1.y + wq1.z*x2.y + wq1.w*x3.y;
    a.z = bv.z + wq2.x*x0.z + wq2.y*x1.z + wq2.z*x2.z + wq2.w*x3.z;
    a.w = bv.w + wq3.x*x0.w + wq3.y*x1.w + wq3.z*x2.w + wq3.w*x3.w;

    float4 v;
    v.x = silu_f(a.x); v.y = silu_f(a.y); v.z = silu_f(a.z); v.w = silu_f(a.w);

    ((float4*)xc)[i4] = v;
    ushort4 o;
    o.x = f2bf(v.x); o.y = f2bf(v.y); o.z = f2bf(v.z); o.w = f2bf(v.w);
    ((ushort4*)xcb)[i4] = o;
}

// ---------------------------------------------------------------------------
// Scan pass 1 (LC=16): local scan from h=0; emit h[16] + S=sum(dt).
// ---------------------------------------------------------------------------
__global__ __launch_bounds__(256) void scan_part1(const float* __restrict__ xdbl,
                                                  const float* __restrict__ xc,
                                                  float* __restrict__ hfin,
                                                  float* __restrict__ Ssum)
{
    __shared__ float Bsh[LC][NS];   // 1 KB

    const int tid = threadIdx.x;
    const int idx = blockIdx.x * 256 + tid;   // (b, c, d)
    const int d   = idx & (DIMD - 1);
    const int bc  = idx >> 10;
    const int c   = bc & (NC - 1);
    const int b   = bc >> 7;
    const int l0  = c * LC;

    const float* xdbl_p = xdbl + ((size_t)b * LL + l0) * XD_N;
    const float* xc_p   = xc   + ((size_t)b * LL + l0) * DIMD + d;

    if (tid < LC * NS / 4) {               // 64 threads stage 16x16 B block
        const int l = tid >> 2, q = tid & 3;
        ((float4*)&Bsh[l][0])[q] = ((const float4*)(xdbl_p + (size_t)l * XD_N))[q];
    }
    __syncthreads();

    float raw[LC], xcv[LC];
    #pragma unroll
    for (int i = 0; i < LC; ++i) raw[i] = xdbl_p[(size_t)i * XD_N + 2 * NS + d];
    #pragma unroll
    for (int i = 0; i < LC; ++i) xcv[i] = xc_p[(size_t)i * DIMD];

    float e[LC], dx[LC];
    float S = 0.f;
    #pragma unroll
    for (int i = 0; i < LC; ++i) {
        float dt, ev;
        dt_decay(raw[i], dt, ev);
        S += dt;
        e[i]  = ev;
        dx[i] = dt * xcv[i];
    }

    float h[NS];
    #pragma unroll
    for (int n = 0; n < NS; ++n) h[n] = 0.f;

    #pragma unroll
    for (int i = 0; i < LC; ++i) {
        const float4* BC = (const float4*)&Bsh[i][0];
        const float4 B0 = BC[0], B1 = BC[1], B2 = BC[2], B3 = BC[3];
        const float ev = e[i], dxv = dx[i];
        const float e2 = ev * ev, e4 = e2 * e2;
        float p0 = ev, p1 = e2, p2 = e2 * ev, p3 = e4;
        h[0]  = fmaf(h[0],  p0, dxv * B0.x);
        h[1]  = fmaf(h[1],  p1, dxv * B0.y);
        h[2]  = fmaf(h[2],  p2, dxv * B0.z);
        h[3]  = fmaf(h[3],  p3, dxv * B0.w);
        p0 *= e4; p1 *= e4; p2 *= e4; p3 *= e4;
        h[4]  = fmaf(h[4],  p0, dxv * B1.x);
        h[5]  = fmaf(h[5],  p1, dxv * B1.y);
        h[6]  = fmaf(h[6],  p2, dxv * B1.z);
        h[7]  = fmaf(h[7],  p3, dxv * B1.w);
        p0 *= e4; p1 *= e4; p2 *= e4; p3 *= e4;
        h[8]  = fmaf(h[8],  p0, dxv * B2.x);
        h[9]  = fmaf(h[9],  p1, dxv * B2.y);
        h[10] = fmaf(h[10], p2, dxv * B2.z);
        h[11] = fmaf(h[11], p3, dxv * B2.w);
        p0 *= e4; p1 *= e4; p2 *= e4; p3 *= e4;
        h[12] = fmaf(h[12], p0, dxv * B3.x);
        h[13] = fmaf(h[13], p1, dxv * B3.y);
        h[14] = fmaf(h[14], p2, dxv * B3.z);
        h[15] = fmaf(h[15], p3, dxv * B3.w);
    }

    float4* hf = (float4*)(hfin + (size_t)idx * NS);
    #pragma unroll
    for (int n = 0; n < 4; ++n) hf[n] = ((float4*)h)[n];
    Ssum[idx] = S;
}

// ---------------------------------------------------------------------------
// Scan pass 2: batched 8-wide prefetch + off-chain __expf; hfin rewritten
// in place to carry-in states.
// ---------------------------------------------------------------------------
__global__ __launch_bounds__(256) void scan_combine(float* __restrict__ hfin,
                                                    const float* __restrict__ Ssum)
{
    const int idx = blockIdx.x * blockDim.x + threadIdx.x;  // B*DIMD*NS
    const int n = idx & (NS - 1);
    const int d = (idx >> 4) & (DIMD - 1);
    const int b = idx >> 14;
    const float np1 = (float)(n + 1);

    float hc = 0.f;
    for (int c0 = 0; c0 < NC; c0 += 8) {
        float Sb[8], hb[8], eb[8];
        #pragma unroll
        for (int j = 0; j < 8; ++j) {
            const size_t base = ((size_t)(b * NC + c0 + j) * DIMD + d);
            Sb[j] = Ssum[base];
            hb[j] = hfin[base * NS + n];
        }
        #pragma unroll
        for (int j = 0; j < 8; ++j) eb[j] = __expf(-Sb[j] * np1);
        #pragma unroll
        for (int j = 0; j < 8; ++j) {
            const size_t o = ((size_t)(b * NC + c0 + j) * DIMD + d) * NS + n;
            hfin[o] = hc;
            hc = fmaf(hc, eb[j], hb[j]);
        }
    }
}

// ---------------------------------------------------------------------------
// Scan pass 3 (LC=16): seeded re-scan + y + D*xc + z-gate + bf16 store.
// ---------------------------------------------------------------------------
__global__ __launch_bounds__(256) void scan_part2(const float* __restrict__ xdbl,
                                                  const float* __restrict__ xc,
                                                  const unsigned short* __restrict__ zb,
                                                  const float* __restrict__ hfin,
                                                  const float* __restrict__ Dp,
                                                  unsigned short* __restrict__ yout)
{
    __shared__ float BCs[LC][2 * NS];   // 2 KB

    const int tid = threadIdx.x;
    const int idx = blockIdx.x * 256 + tid;
    const int d   = idx & (DIMD - 1);
    const int bc  = idx >> 10;
    const int c   = bc & (NC - 1);
    const int b   = bc >> 7;
    const int l0  = c * LC;

    const float* xdbl_p = xdbl + ((size_t)b * LL + l0) * XD_N;
    const float* xc_p   = xc   + ((size_t)b * LL + l0) * DIMD + d;
    const unsigned short* zb_p = zb + ((size_t)b * LL + l0) * DIMD + d;
    unsigned short* y_p = yout + ((size_t)b * LL + l0) * DIMD + d;

    if (tid < LC * 2 * NS / 4) {           // 128 threads stage 16x32 B|C block
        const int l = tid >> 3, q = tid & 7;
        ((float4*)&BCs[l][0])[q] = ((const float4*)(xdbl_p + (size_t)l * XD_N))[q];
    }
    __syncthreads();

    float raw[LC], xcv[LC], zg[LC];
    #pragma unroll
    for (int i = 0; i < LC; ++i) raw[i] = xdbl_p[(size_t)i * XD_N + 2 * NS + d];
    #pragma unroll
    for (int i = 0; i < LC; ++i) xcv[i] = xc_p[(size_t)i * DIMD];
    #pragma unroll
    for (int i = 0; i < LC; ++i) zg[i] = bf2f(zb_p[(size_t)i * DIMD]);

    float e[LC], dx[LC];
    #pragma unroll
    for (int i = 0; i < LC; ++i) {
        float dt, ev;
        dt_decay(raw[i], dt, ev);
        e[i]  = ev;
        dx[i] = dt * xcv[i];
    }

    const float Dv = Dp[d];
    float h[NS];
    {
        const float4* hf = (const float4*)(hfin + (size_t)idx * NS);
        #pragma unroll
        for (int n = 0; n < 4; ++n) ((float4*)h)[n] = hf[n];
    }

    #pragma unroll
    for (int i = 0; i < LC; ++i) {
        const float4* BC = (const float4*)&BCs[i][0];
        const float4 B0 = BC[0], B1 = BC[1], B2 = BC[2], B3 = BC[3];
        const float4 C0 = BC[4], C1 = BC[5], C2 = BC[6], C3 = BC[7];
        const float ev = e[i], dxv = dx[i];
        const float e2 = ev * ev, e4 = e2 * e2;
        float p0 = ev, p1 = e2, p2 = e2 * ev, p3 = e4;
        float y0, y1, y2, y3;
        h[0]  = fmaf(h[0],  p0, dxv * B0.x); y0 = h[0]  * C0.x;
        h[1]  = fmaf(h[1],  p1, dxv * B0.y); y1 = h[1]  * C0.y;
        h[2]  = fmaf(h[2],  p2, dxv * B0.z); y2 = h[2]  * C0.z;
        h[3]  = fmaf(h[3],  p3, dxv * B0.w); y3 = h[3]  * C0.w;
        p0 *= e4; p1 *= e4; p2 *= e4; p3 *= e4;
        h[4]  = fmaf(h[4],  p0, dxv * B1.x); y0 = fmaf(h[4],  C1.x, y0);
        h[5]  = fmaf(h[5],  p1, dxv * B1.y); y1 = fmaf(h[5],  C1.y, y1);
        h[6]  = fmaf(h[6],  p2, dxv * B1.z); y2 = fmaf(h[6],  C1.z, y2);
        h[7]  = fmaf(h[7],  p3, dxv * B1.w); y3 = fmaf(h[7],  C1.w, y3);
        p0 *= e4; p1 *= e4; p2 *= e4; p3 *= e4;
        h[8]  = fmaf(h[8],  p0, dxv * B2.x); y0 = fmaf(h[8],  C2.x, y0);
        h[9]  = fmaf(h[9],  p1, dxv * B2.y); y1 = fmaf(h[9],  C2.y, y1);
        h[10] = fmaf(h[10], p2, dxv * B2.z); y2 = fmaf(h[10], C2.z, y2);
        h[11] = fmaf(h[11], p3, dxv * B2.w); y3 = fmaf(h[11], C2.w, y3);
        p0 *= e4; p1 *= e4; p2 *= e4; p3 *= e4;
        h[12] = fmaf(h[12], p0, dxv * B3.x); y0 = fmaf(h[12], C3.x, y0);
        h[13] = fmaf(h[13], p1, dxv * B3.y); y1 = fmaf(h[13], C3.y, y1);
        h[14] = fmaf(h[14], p2, dxv * B3.z); y2 = fmaf(h[14], C3.z, y2);
        h[15] = fmaf(h[15], p3, dxv * B3.w); y3 = fmaf(h[15], C3.w, y3);

        const float y  = (y0 + y1) + (y2 + y3);
        const float yv = fmaf(Dv, xcv[i], y);
        y_p[(size_t)i * DIMD] = f2bf(yv * zg[i]);
    }
}

extern "C" void kernel_launch(void* const* d_in, const int* in_sizes, int n_in,
                              void* d_out, int out_size, void* d_ws, size_t ws_size,
                              hipStream_t stream)
{
    const float* x          = (const float*)d_in[0];
    const float* in_proj_w  = (const float*)d_in[1];
    const float* conv_w     = (const float*)d_in[2];
    const float* conv_b     = (const float*)d_in[3];
    const float* x_proj_w   = (const float*)d_in[4];
    const float* D_param    = (const float*)d_in[5];
    const float* out_proj_w = (const float*)d_in[6];
    float* out = (float*)d_out;

    // workspace layout (~103 MiB of ~268 MiB ws)
    float* xcraw = (float*)d_ws;                              // ML*DIMD f32
    float* xc    = xcraw + (size_t)ML * DIMD;                 // ML*DIMD f32
    float* xdbl  = xc    + (size_t)ML * DIMD;                 // ML*XD_N f32
    unsigned short* zb  = (unsigned short*)(xdbl + (size_t)ML * XD_N); // ML*DIMD bf16
    unsigned short* xb  = zb  + (size_t)ML * DIMD;            // ML*DIMD bf16
    unsigned short* xcb = xb  + (size_t)ML * DIMD;            // ML*DIMD bf16
    unsigned short* wb1 = xcb + (size_t)ML * DIMD;            // XZ_N*DIMD bf16
    unsigned short* wb2 = wb1 + (size_t)XZ_N * DIMD;          // XD_N*DIMD bf16
    unsigned short* wb3 = wb2 + (size_t)XD_N * DIMD;          // DIMD*DIMD bf16
    float* hfin = (float*)(wb3 + (size_t)DIMD * DIMD);        // B*NC*DIMD*NS f32
    float* Ssum = hfin + (size_t)BB * NC * DIMD * NS;         // B*NC*DIMD f32
    unsigned short* yb  = xb;    // xb dead after GEMM1; reuse for scan output

    const int n0 = ML * DIMD / 4, n1 = XZ_N * DIMD / 4,
              n2 = XD_N * DIMD / 4, n3 = DIMD * DIMD / 4;
    const int ncvt = n0 + n1 + n2 + n3;

    // 0) all f32->bf16 conversions in one launch
    cvt_all<<<(ncvt + 255) / 256, 256, 0, stream>>>(
        x, xb, n0, in_proj_w, wb1, n1, x_proj_w, wb2, n2, out_proj_w, wb3, n3);

    // 1) xz = x @ in_proj_w.T; x_c half -> f32 xcraw, z half -> silu bf16 zb
    gemm_mfma_bt<<<dim3(XZ_N / 64, ML / 128), 256, 0, stream>>>(
        xb, wb1, xcraw, zb, ML, XZ_N, DIMD, DIMD);

    // 2) depthwise conv + bias + silu -> xc (f32) + xcb (bf16)
    conv_silu<<<(ML * DIMD / 4) / 256, 256, 0, stream>>>(
        xcraw, conv_w, conv_b, xc, xcb);

    // 3) x_dbl = xc @ x_proj_w.T     (4096 x 1056 x 1024)
    gemm_mfma_bt<<<dim3((XD_N + 63) / 64, ML / 128), 256, 0, stream>>>(
        xcb, wb2, xdbl, nullptr, ML, XD_N, DIMD, XD_N);

    // 4) chunked selective scan (LC=16, 1024 blocks). Do NOT grid.sync-fuse
    //    (R9: grid sync forces per-XCD L2 writeback -> 577 MB HBM, 465 us).
    scan_part1<<<(BB * NC * DIMD) / 256, 256, 0, stream>>>(xdbl, xc, hfin, Ssum);
    scan_combine<<<(BB * DIMD * NS) / 256, 256, 0, stream>>>(hfin, Ssum);
    scan_part2<<<(BB * NC * DIMD) / 256, 256, 0, stream>>>(xdbl, xc, zb, hfin,
                                                           D_param, yb);

    // 5) out = y @ out_proj_w.T      (4096 x 1024 x 1024)
    gemm_mfma_bt<<<dim3(DIMD / 64, ML / 128), 256, 0, stream>>>(
        yb, wb3, out, nullptr, ML, DIMD, DIMD, DIMD);
}